// Round 8
// baseline (262.716 us; speedup 1.0000x reference)
//
#include <hip/hip_runtime.h>
#include <stdint.h>

typedef unsigned short u16;
typedef unsigned int   u32;
typedef __bf16 bf16_t;
typedef bf16_t bf16x8 __attribute__((ext_vector_type(8)));
typedef u16    u16x8  __attribute__((ext_vector_type(8)));
typedef float  f32x4  __attribute__((ext_vector_type(4)));
typedef float  f32x16 __attribute__((ext_vector_type(16)));

#define NB   2
#define NL   2048
#define ND   2048
#define NHQ  32
#define NHKV 8
#define NHD  64
#define NQKV 3072   // D + 2*HKV*HD
#define QSCALE 0.18033688011112042f   // 0.125 * log2(e): softmax runs in exp2 domain

__device__ __forceinline__ u16 f2bf(float x){
  union{float f;u32 u;} v; v.f = x;
  u32 r = v.u + 0x7FFFu + ((v.u >> 16) & 1u);   // RTNE
  return (u16)(r >> 16);
}
__device__ __forceinline__ float bf2f(u16 b){
  union{u32 u;float f;} v; v.u = ((u32)b) << 16; return v.f;
}

__device__ __forceinline__ float exp2_hw(float x){
#if __has_builtin(__builtin_amdgcn_exp2f)
  return __builtin_amdgcn_exp2f(x);
#else
  float r; asm("v_exp_f32 %0, %1" : "=v"(r) : "v"(x)); return r;
#endif
}

__device__ __forceinline__ void gload_lds16(const void* g, void* l){
  auto gp = reinterpret_cast<__attribute__((address_space(1))) u16*>(
      (uintptr_t)g);
  auto lp = reinterpret_cast<__attribute__((address_space(3))) u16*>(
      (uintptr_t)l);
  __builtin_amdgcn_global_load_lds(gp, lp, 16, 0, 0);
}

__device__ __forceinline__ f32x4 mfma16(bf16x8 a, bf16x8 b, f32x4 c){
  return __builtin_amdgcn_mfma_f32_16x16x32_bf16(a, b, c, 0, 0, 0);
}
__device__ __forceinline__ f32x16 mfma32(bf16x8 a, bf16x8 b, f32x16 c){
  return __builtin_amdgcn_mfma_f32_32x32x16_bf16(a, b, c, 0, 0, 0);
}
__device__ __forceinline__ u32 cvtpk(float lo, float hi){
  u32 w;
  asm("v_cvt_pk_bf16_f32 %0, %1, %2" : "=v"(w) : "v"(lo), "v"(hi));
  return w;
}

// ---------------- fp32 -> bf16 convert (vectorized) ----------------
__global__ void k_cvt(const float* __restrict__ in, u16* __restrict__ out, int n4){
  int i = blockIdx.x * blockDim.x + threadIdx.x;
  if (i >= n4) return;
  float4 f = reinterpret_cast<const float4*>(in)[i];
  ushort4 o;
  o.x = f2bf(f.x); o.y = f2bf(f.y); o.z = f2bf(f.z); o.w = f2bf(f.w);
  reinterpret_cast<ushort4*>(out)[i] = o;
}

// ---------------- RoPE cos/sin table [L][32] ----------------
__global__ void k_rope_tab(const int* __restrict__ pos, float* __restrict__ cosT,
                           float* __restrict__ sinT){
  int idx = blockIdx.x * 256 + threadIdx.x;      // 65536 total
  int l = idx >> 5, i = idx & 31;
  float p = (float)pos[l];
  float inv = __expf(-((float)i * (1.0f/32.0f)) * 9.210340371976184f); // ln(1e4)
  float fr = p * inv;
  cosT[idx] = cosf(fr);
  sinT[idx] = sinf(fr);
}

// ---------------- bf16 NT GEMM: C[M][N] = A[M][K] * B[N][K]^T ----------------
template<int WRITE_F32>
__global__ __launch_bounds__(256) void k_gemm_nt(const u16* __restrict__ A,
                                                 const u16* __restrict__ Bm,
                                                 void* __restrict__ Cp,
                                                 int M, int N, int K){
  __shared__ u16 As[128*32];
  __shared__ u16 Bs[128*32];
  const int tid = threadIdx.x;
  const int lane = tid & 63;
  const int w = tid >> 6;
  const int wr = w >> 1, wc = w & 1;
  const int tm = blockIdx.y * 128, tn = blockIdx.x * 128;
  const int lr = lane & 15, lg = lane >> 4;

  const int ca = 2*w, cb = 2*w+1;
  const u16* pa0 = A  + (size_t)(tm + ca*16 + (lane>>2))*K + (lane&3)*8;
  const u16* pa1 = A  + (size_t)(tm + cb*16 + (lane>>2))*K + (lane&3)*8;
  const u16* pb0 = Bm + (size_t)(tn + ca*16 + (lane>>2))*K + (lane&3)*8;
  const u16* pb1 = Bm + (size_t)(tn + cb*16 + (lane>>2))*K + (lane&3)*8;
  u16* la0 = &As[ca*512];
  u16* la1 = &As[cb*512];
  u16* lb0 = &Bs[ca*512];
  u16* lb1 = &Bs[cb*512];

  f32x4 acc[4][4] = {};

  const int nk = K >> 5;
  for (int kt = 0; kt < nk; ++kt){
    gload_lds16(pa0, la0);
    gload_lds16(pa1, la1);
    gload_lds16(pb0, lb0);
    gload_lds16(pb1, lb1);
    pa0 += 32; pa1 += 32; pb0 += 32; pb1 += 32;
    __syncthreads();
    bf16x8 af[4], bfr[4];
#pragma unroll
    for (int m = 0; m < 4; ++m)
      af[m] = *reinterpret_cast<const bf16x8*>(&As[(wr*64 + m*16 + lr)*32 + lg*8]);
#pragma unroll
    for (int n = 0; n < 4; ++n)
      bfr[n] = *reinterpret_cast<const bf16x8*>(&Bs[(wc*64 + n*16 + lr)*32 + lg*8]);
#pragma unroll
    for (int m = 0; m < 4; ++m)
#pragma unroll
      for (int n = 0; n < 4; ++n)
        acc[m][n] = mfma16(af[m], bfr[n], acc[m][n]);
    __syncthreads();
  }

  const int rbase = tm + wr*64 + lg*4;
  const int cbase = tn + wc*64 + lr;
#pragma unroll
  for (int m = 0; m < 4; ++m){
#pragma unroll
    for (int n = 0; n < 4; ++n){
#pragma unroll
      for (int r = 0; r < 4; ++r){
        size_t off = (size_t)(rbase + m*16 + r)*N + (cbase + n*16);
        if (WRITE_F32) ((float*)Cp)[off] = acc[m][n][r];
        else           ((u16*)Cp)[off]   = f2bf(acc[m][n][r]);
      }
    }
  }
}

// ---------------- RoPE + scatter ----------------
__global__ void k_rope_scatter(const u16* __restrict__ qkv, const float* __restrict__ cosT,
                               const float* __restrict__ sinT,
                               u16* __restrict__ Q, u16* __restrict__ Ko, u16* __restrict__ V){
  const int row = blockIdx.x;                 // b*L + l
  const int b = row >> 11, l = row & 2047;
  const int t = threadIdx.x;
#pragma unroll
  for (int it = 0; it < 6; ++it){
    int pp = t + it*256;
    u32 xin = *reinterpret_cast<const u32*>(&qkv[(size_t)row*NQKV + pp*2]);
    float x1 = bf2f((u16)(xin & 0xFFFFu));
    float x2 = bf2f((u16)(xin >> 16));
    if (pp < 1280){
      int i = pp & 31;
      float c = cosT[l*32 + i], s = sinT[l*32 + i];
      float y1 = x1*c - x2*s;
      float y2 = x1*s + x2*c;
      if (pp < 1024){
        int hh = pp >> 5, d = (pp & 31)*2;
        u32 o = (u32)f2bf(y1*QSCALE) | ((u32)f2bf(y2*QSCALE) << 16);
        *reinterpret_cast<u32*>(&Q[(((size_t)(b*NHQ + hh))*NL + l)*NHD + d]) = o;
      } else {
        int idx = pp - 1024, kvh = idx >> 5, d = (idx & 31)*2;
        u32 o = (u32)f2bf(y1) | ((u32)f2bf(y2) << 16);
        *reinterpret_cast<u32*>(&Ko[(((size_t)(b*NHKV + kvh))*NL + l)*NHD + d]) = o;
      }
    } else {
      int idx = pp - 1280, kvh = idx >> 5, d = (idx & 31)*2;
      *reinterpret_cast<u32*>(&V[(((size_t)(b*NHKV + kvh))*NL + l)*NHD + d]) = xin;
    }
  }
}

// ---------------- V[b][kvh][l][d] -> VT[b][kvh][d][l] ----------------
__global__ __launch_bounds__(256) void k_transpose(const u16* __restrict__ V, u16* __restrict__ VT){
  __shared__ u16 T[64*72];
  const int bid = blockIdx.x;
  const int slice = bid >> 5, tile = bid & 31;
  const u16* src = V  + (size_t)slice*NL*NHD + (size_t)tile*64*NHD;
  u16*       dst = VT + (size_t)slice*NHD*NL + (size_t)tile*64;
  const int t = threadIdx.x;
  {
    int r = t >> 2, c0 = (t & 3)*16;
    const u16x8* s = reinterpret_cast<const u16x8*>(src + (size_t)r*NHD + c0);
    *reinterpret_cast<u16x8*>(&T[r*72 + c0])     = s[0];
    *reinterpret_cast<u16x8*>(&T[r*72 + c0 + 8]) = s[1];
  }
  __syncthreads();
  {
    int d = t >> 2, l0 = (t & 3)*16;
    u16x8 v0, v1;
#pragma unroll
    for (int j = 0; j < 8; ++j) v0[j] = T[(l0+j)*72 + d];
#pragma unroll
    for (int j = 0; j < 8; ++j) v1[j] = T[(l0+8+j)*72 + d];
    u16* dp = dst + (size_t)d*NL + l0;
    *reinterpret_cast<u16x8*>(dp)     = v0;
    *reinterpret_cast<u16x8*>(dp + 8) = v1;
  }
}

// ---------------- causal GQA flash attention: LDS-staged dual-stream ----------------
// R7 lesson: {4m..4m+3} blocks have 2..32 KV-tile trips -> 1.8x makespan tail.
// Fix: each wave owns the COMPLEMENTARY pair qA=4mb+w, qB=63-qA. Both streams
// consume the same KV tiles from 0, so one LDS staging serves both; per-wave
// compute = ntA+ntB ~ 34 = constant -> every block equal work, no tail.
// One kf/vf LDS read feeds both streams; A/B chains give the scheduler
// independent MFMA/VALU work to overlap.
__device__ __forceinline__ void stage_kv(const u16* __restrict__ Kp, const u16* __restrict__ VTp,
                                         int kvb, u16* lk, u16* lv, int w, int lane){
  const char* ks = (const char*)(Kp + (size_t)kvb*NHD);     // 8KB contiguous
  const char* vs = (const char*)VTp + (size_t)kvb*2;        // 64 rows, stride NL*2
  const int o0 = w*1024 + lane*16;
#pragma unroll
  for (int i = 0; i < 2; ++i){
    int o  = o0 + i*4096;
    int sw = o ^ (((o>>7)&7)<<4);                           // inverse-swizzled source
    gload_lds16(ks + sw, (char*)lk + w*1024 + i*4096);      // LDS base wave-uniform
    int d = o>>7, c = o&127;
    gload_lds16(vs + (size_t)d*(NL*2) + (c ^ ((d&7)<<4)), (char*)lv + w*1024 + i*4096);
  }
}
__device__ __forceinline__ bf16x8 lds16(const u16* base, int row, int colb){
  return *reinterpret_cast<const bf16x8*>((const char*)base + row*128 + (colb ^ ((row&7)<<4)));
}

// One stream's softmax+PV for the current tile (S already computed).
__device__ __forceinline__ void sm_pv(f32x16& s0, f32x16& s1, f32x16& o0, f32x16& o1,
                                      float& mrun, float& lsum, const bf16x8 vf[8],
                                      int kvb, int qrow, int hi, bool mask){
  float pv[32];
#pragma unroll
  for (int r = 0; r < 16; ++r){ pv[r] = s0[r]; pv[16+r] = s1[r]; }
  if (mask){                                   // wave-uniform branch
#pragma unroll
    for (int r = 0; r < 16; ++r){
      const int kl = (r&3) + 8*(r>>2) + 4*hi;
      pv[r]    = (kvb + kl      <= qrow) ? pv[r]    : -1e30f;
      pv[16+r] = (kvb + 32 + kl <= qrow) ? pv[16+r] : -1e30f;
    }
  }
  float t[8];
#pragma unroll
  for (int r = 0; r < 8; ++r)  t[r] = fmaxf(fmaxf(pv[r], pv[r+8]), pv[r+16]);
#pragma unroll
  for (int r = 0; r < 4; ++r)  t[r] = fmaxf(fmaxf(t[r], t[r+4]), pv[24+r]);
  t[0] = fmaxf(fmaxf(t[0], t[1]), fmaxf(t[2], t[3]));
  const float mnew = fmaxf(t[0], __shfl_xor(t[0], 32));
  if (__any(mnew - mrun > 8.0f)){              // defer-max (T13)
    const float mupd = fmaxf(mrun, mnew);
    const float c = exp2_hw(mrun - mupd);
    lsum *= c;
#pragma unroll
    for (int r = 0; r < 16; ++r){ o0[r] *= c; o1[r] *= c; }
    mrun = mupd;
  }
  float p[32];
#pragma unroll
  for (int r = 0; r < 32; ++r) p[r] = exp2_hw(pv[r] - mrun);
  float u[16];
#pragma unroll
  for (int r = 0; r < 16; ++r) u[r] = p[r] + p[16+r];
#pragma unroll
  for (int r = 0; r < 8; ++r)  u[r] += u[r+8];
#pragma unroll
  for (int r = 0; r < 4; ++r)  u[r] += u[r+4];
  lsum += (u[0]+u[1]) + (u[2]+u[3]);
  u32 wds[16];
#pragma unroll
  for (int i = 0; i < 16; ++i) wds[i] = cvtpk(p[2*i], p[2*i+1]);
  bf16x8 pf[4];
#pragma unroll
  for (int fi = 0; fi < 4; ++fi){
    u32 x  = wds[4*fi+0], y  = wds[4*fi+2];
    u32 x2 = wds[4*fi+1], y2 = wds[4*fi+3];
    asm("v_permlane32_swap_b32 %0, %1" : "+v"(x),  "+v"(y));
    asm("v_permlane32_swap_b32 %0, %1" : "+v"(x2), "+v"(y2));
    union { u32 wq[4]; bf16x8 v; } uu;
    uu.wq[0] = x; uu.wq[1] = x2; uu.wq[2] = y; uu.wq[3] = y2;
    pf[fi] = uu.v;
  }
  __builtin_amdgcn_s_setprio(1);
#pragma unroll
  for (int ks = 0; ks < 4; ++ks){
    o0 = mfma32(vf[ks],   pf[ks], o0);
    o1 = mfma32(vf[4+ks], pf[ks], o1);
  }
  __builtin_amdgcn_s_setprio(0);
}

__device__ __forceinline__ void store_o(const f32x16& o0, const f32x16& o1, float lsum,
                                        u16* O, int b, int h, int qrow, int hi){
  float lt = lsum + __shfl_xor(lsum, 32);
  const float inv = 1.0f / lt;
  u16* Op = O + ((size_t)(b*NL + qrow))*ND + h*NHD;
#pragma unroll
  for (int md = 0; md < 2; ++md){
#pragma unroll
    for (int q4 = 0; q4 < 4; ++q4){
      ushort4 sv;
      float a0 = (md ? o1[4*q4+0] : o0[4*q4+0]) * inv;
      float a1 = (md ? o1[4*q4+1] : o0[4*q4+1]) * inv;
      float a2 = (md ? o1[4*q4+2] : o0[4*q4+2]) * inv;
      float a3 = (md ? o1[4*q4+3] : o0[4*q4+3]) * inv;
      sv.x = f2bf(a0); sv.y = f2bf(a1); sv.z = f2bf(a2); sv.w = f2bf(a3);
      *reinterpret_cast<ushort4*>(&Op[md*32 + 8*q4 + 4*hi]) = sv;
    }
  }
}

__global__ __launch_bounds__(256) void k_attn5(const u16* __restrict__ Q, const u16* __restrict__ Kg,
                                               const u16* __restrict__ VT, u16* __restrict__ O){
  __shared__ u16 LK[2][4096];
  __shared__ u16 LV[2][4096];
  const int tid = threadIdx.x, lane = tid & 63, w = tid >> 6;
  const int q32 = lane & 31, hi = lane >> 5;
  const int f = blockIdx.x;                    // 0..511
  const int xcd = f & 7, rest = f >> 3;        // cluster (b,kvh) per XCD for KV L2 reuse
  const int grp = xcd*2 + (rest >> 5);         // 0..15 = (b,kvh)
  const int sub = rest & 31;
  const int b = grp >> 3, kvh = grp & 7;
  const int h = kvh*4 + (sub >> 3);
  const int mb = sub & 7;
  const int qtA = 4*mb + w, qtB = 63 - qtA;
  const u16* Qp  = Q  + ((size_t)(b*NHQ  + h  ))*NL*NHD;
  const u16* Kp  = Kg + ((size_t)(b*NHKV + kvh))*NL*NHD;
  const u16* VTp = VT + ((size_t)(b*NHKV + kvh))*NHD*NL;

  const int qrowA = qtA*32 + q32, qrowB = qtB*32 + q32;
  const int ntA = (qtA*32 + 95) >> 6;
  const int ntB = (qtB*32 + 95) >> 6;
  const int ntblk = ((63 - 4*mb)*32 + 95) >> 6;   // wave 0's ntB = block max

  bf16x8 qfA[4], qfB[4];
#pragma unroll
  for (int ks = 0; ks < 4; ++ks){
    qfA[ks] = *reinterpret_cast<const bf16x8*>(&Qp[(size_t)qrowA*NHD + ks*16 + hi*8]);
    qfB[ks] = *reinterpret_cast<const bf16x8*>(&Qp[(size_t)qrowB*NHD + ks*16 + hi*8]);
  }

  f32x16 oA0 = {}, oA1 = {}, oB0 = {}, oB1 = {};
  float mA = -1e30f, lA = 0.0f, mB = -1e30f, lB = 0.0f;

  stage_kv(Kp, VTp, 0, LK[0], LV[0], w, lane);
  __syncthreads();

#pragma unroll 1
  for (int j = 0; j < ntblk; ++j){
    const int cur = j & 1;
    const u16* lk = LK[cur];
    const u16* lv = LV[cur];
    if (j + 1 < ntblk)
      stage_kv(Kp, VTp, (j+1) << 6, LK[cur^1], LV[cur^1], w, lane);

    const bool actA = j < ntA, actB = j < ntB;
    if (actB){
      const int kvb = j << 6;
      bf16x8 kf[8];
#pragma unroll
      for (int ks = 0; ks < 4; ++ks){
        kf[ks]   = lds16(lk, q32,      ks*32 + hi*16);
        kf[4+ks] = lds16(lk, 32 + q32, ks*32 + hi*16);
      }
      // ---- QK^T for both streams off one kf ----
      f32x16 sB0 = {}, sB1 = {}, sA0 = {}, sA1 = {};
      __builtin_amdgcn_s_setprio(1);
#pragma unroll
      for (int ks = 0; ks < 4; ++ks){
        sB0 = mfma32(kf[ks],   qfB[ks], sB0);
        sB1 = mfma32(kf[4+ks], qfB[ks], sB1);
      }
      if (actA){
#pragma unroll
        for (int ks = 0; ks < 4; ++ks){
          sA0 = mfma32(kf[ks],   qfA[ks], sA0);
          sA1 = mfma32(kf[4+ks], qfA[ks], sA1);
        }
      }
      __builtin_amdgcn_s_setprio(0);
      bf16x8 vf[8];
#pragma unroll
      for (int ks = 0; ks < 4; ++ks){
        vf[ks]   = lds16(lv, q32,      ks*32 + hi*16);
        vf[4+ks] = lds16(lv, 32 + q32, ks*32 + hi*16);
      }
      sm_pv(sB0, sB1, oB0, oB1, mB, lB, vf, kvb, qrowB, hi, j == ntB-1);
      if (actA)
        sm_pv(sA0, sA1, oA0, oA1, mA, lA, vf, kvb, qrowA, hi, j == ntA-1);
    }
    __syncthreads();
  }

  store_o(oA0, oA1, lA, O, b, h, qrowA, hi);
  store_o(oB0, oB1, lB, O, b, h, qrowB, hi);
}

extern "C" void kernel_launch(void* const* d_in, const int* in_sizes, int n_in,
                              void* d_out, int out_size, void* d_ws, size_t ws_size,
                              hipStream_t stream){
  (void)in_sizes; (void)n_in; (void)out_size; (void)ws_size;
  const float* x   = (const float*)d_in[0];
  const int*   pos = (const int*)  d_in[1];
  const float* wq  = (const float*)d_in[2];
  const float* wk  = (const float*)d_in[3];
  const float* wv  = (const float*)d_in[4];
  const float* wo  = (const float*)d_in[5];

  char* ws = (char*)d_ws;
  size_t off = 0;
  auto alloc = [&](size_t bytes) -> void* {
    void* p = ws + off;
    off += (bytes + 255) & ~(size_t)255;
    return p;
  };
  const size_t n_x   = (size_t)NB*NL*ND;
  const size_t n_wq  = (size_t)ND*ND;
  const size_t n_wkv = (size_t)NHKV*NHD*ND;

  u16* xb    = (u16*)alloc(n_x*2);                       // reused as attn output O
  u16* wqkvb = (u16*)alloc((size_t)NQKV*ND*2);
  u16* wob   = (u16*)alloc(n_wq*2);
  u16* qkv   = (u16*)alloc((size_t)NB*NL*NQKV*2);
  u16* Qb    = (u16*)alloc((size_t)NB*NHQ*NL*NHD*2);
  u16* Kb    = (u16*)alloc((size_t)NB*NHKV*NL*NHD*2);
  u16* Vb    = (u16*)alloc((size_t)NB*NHKV*NL*NHD*2);
  u16* VTb   = (u16*)alloc((size_t)NB*NHKV*NHD*NL*2);
  float* cosT= (float*)alloc((size_t)NL*32*4);
  float* sinT= (float*)alloc((size_t)NL*32*4);

  k_cvt<<<(int)(n_x/4/256),   256, 0, stream>>>(x,  xb, (int)(n_x/4));
  k_cvt<<<(int)(n_wq/4/256),  256, 0, stream>>>(wq, wqkvb, (int)(n_wq/4));
  k_cvt<<<(int)(n_wkv/4/256), 256, 0, stream>>>(wk, wqkvb + n_wq, (int)(n_wkv/4));
  k_cvt<<<(int)(n_wkv/4/256), 256, 0, stream>>>(wv, wqkvb + n_wq + n_wkv, (int)(n_wkv/4));
  k_cvt<<<(int)(n_wq/4/256),  256, 0, stream>>>(wo, wob, (int)(n_wq/4));
  k_rope_tab<<<(NL*32)/256, 256, 0, stream>>>(pos, cosT, sinT);

  k_gemm_nt<0><<<dim3(NQKV/128, (NB*NL)/128), 256, 0, stream>>>(xb, wqkvb, qkv, NB*NL, NQKV, ND);
  k_rope_scatter<<<NB*NL, 256, 0, stream>>>(qkv, cosT, sinT, Qb, Kb, Vb);
  k_transpose<<<NB*NHKV*(NL/64), 256, 0, stream>>>(Vb, VTb);
  k_attn5<<<512, 256, 0, stream>>>(Qb, Kb, VTb, xb);
  k_gemm_nt<1><<<dim3(ND/128, (NB*NL)/128), 256, 0, stream>>>(xb, wob, d_out, NB*NL, ND, ND);
}

// Round 9
// 245.333 us; speedup vs baseline: 1.0709x; 1.0709x over previous
//
#include <hip/hip_runtime.h>
#include <stdint.h>

typedef unsigned short u16;
typedef unsigned int   u32;
typedef __bf16 bf16_t;
typedef bf16_t bf16x8 __attribute__((ext_vector_type(8)));
typedef u16    u16x8  __attribute__((ext_vector_type(8)));
typedef float  f32x4  __attribute__((ext_vector_type(4)));
typedef float  f32x16 __attribute__((ext_vector_type(16)));

#define NB   2
#define NL   2048
#define ND   2048
#define NHQ  32
#define NHKV 8
#define NHD  64
#define NQKV 3072   // D + 2*HKV*HD
#define QSCALE 0.18033688011112042f   // 0.125 * log2(e): softmax runs in exp2 domain
#define SM_SHIFT 24.0f                // fixed softmax shift (logit bound << 24; shift cancels in O/lsum)

__device__ __forceinline__ u16 f2bf(float x){
  union{float f;u32 u;} v; v.f = x;
  u32 r = v.u + 0x7FFFu + ((v.u >> 16) & 1u);   // RTNE
  return (u16)(r >> 16);
}
__device__ __forceinline__ float bf2f(u16 b){
  union{u32 u;float f;} v; v.u = ((u32)b) << 16; return v.f;
}

__device__ __forceinline__ float exp2_hw(float x){
#if __has_builtin(__builtin_amdgcn_exp2f)
  return __builtin_amdgcn_exp2f(x);
#else
  float r; asm("v_exp_f32 %0, %1" : "=v"(r) : "v"(x)); return r;
#endif
}

__device__ __forceinline__ void gload_lds16(const void* g, void* l){
  auto gp = reinterpret_cast<__attribute__((address_space(1))) u16*>(
      (uintptr_t)g);
  auto lp = reinterpret_cast<__attribute__((address_space(3))) u16*>(
      (uintptr_t)l);
  __builtin_amdgcn_global_load_lds(gp, lp, 16, 0, 0);
}

__device__ __forceinline__ f32x4 mfma16(bf16x8 a, bf16x8 b, f32x4 c){
  return __builtin_amdgcn_mfma_f32_16x16x32_bf16(a, b, c, 0, 0, 0);
}
__device__ __forceinline__ f32x16 mfma32(bf16x8 a, bf16x8 b, f32x16 c){
  return __builtin_amdgcn_mfma_f32_32x32x16_bf16(a, b, c, 0, 0, 0);
}
__device__ __forceinline__ u32 cvtpk(float lo, float hi){
  u32 w;
  asm("v_cvt_pk_bf16_f32 %0, %1, %2" : "=v"(w) : "v"(lo), "v"(hi));
  return w;
}

// ---------------- fused fp32->bf16 converts + RoPE table (one launch) ----------------
// Segments (float4 units): x | wq | wk | wv | wo, then the 65536-entry rope table.
#define CV_S1 2097152   // x
#define CV_S2 3145728   // + wq
#define CV_S3 3407872   // + wk
#define CV_S4 3670016   // + wv
#define CV_S5 4718592   // + wo
#define CV_TOT (CV_S5 + 65536)

__global__ void k_prep(const float* __restrict__ x,  const float* __restrict__ wq,
                       const float* __restrict__ wk, const float* __restrict__ wv,
                       const float* __restrict__ wo, const int* __restrict__ pos,
                       u16* __restrict__ xb, u16* __restrict__ wqkvb, u16* __restrict__ wob,
                       float* __restrict__ cosT, float* __restrict__ sinT){
  int i = blockIdx.x * 256 + threadIdx.x;
  if (i < CV_S5){
    const float4* src; ushort4* dst; int off;
    if (i < CV_S1)      { src = (const float4*)x;  dst = (ushort4*)xb;    off = i; }
    else if (i < CV_S2) { src = (const float4*)wq; dst = (ushort4*)wqkvb; off = i - CV_S1; }
    else if (i < CV_S3) { src = (const float4*)wk; dst = (ushort4*)wqkvb + 1048576; off = i - CV_S2; }
    else if (i < CV_S4) { src = (const float4*)wv; dst = (ushort4*)wqkvb + 1310720; off = i - CV_S3; }
    else                { src = (const float4*)wo; dst = (ushort4*)wob;   off = i - CV_S4; }
    float4 f = src[off];
    ushort4 o;
    o.x = f2bf(f.x); o.y = f2bf(f.y); o.z = f2bf(f.z); o.w = f2bf(f.w);
    dst[off] = o;
  } else {
    int idx = i - CV_S5;                         // 65536 = [L][32]
    int l = idx >> 5, k = idx & 31;
    float p = (float)pos[l];
    float inv = __expf(-((float)k * (1.0f/32.0f)) * 9.210340371976184f); // ln(1e4)
    float fr = p * inv;
    cosT[idx] = cosf(fr);
    sinT[idx] = sinf(fr);
  }
}

// ---------------- bf16 NT GEMM: C[M][N] = A[M][K] * B[N][K]^T ----------------
template<int WRITE_F32>
__global__ __launch_bounds__(256) void k_gemm_nt(const u16* __restrict__ A,
                                                 const u16* __restrict__ Bm,
                                                 void* __restrict__ Cp,
                                                 int M, int N, int K){
  __shared__ u16 As[128*32];
  __shared__ u16 Bs[128*32];
  const int tid = threadIdx.x;
  const int lane = tid & 63;
  const int w = tid >> 6;
  const int wr = w >> 1, wc = w & 1;
  const int tm = blockIdx.y * 128, tn = blockIdx.x * 128;
  const int lr = lane & 15, lg = lane >> 4;

  const int ca = 2*w, cb = 2*w+1;
  const u16* pa0 = A  + (size_t)(tm + ca*16 + (lane>>2))*K + (lane&3)*8;
  const u16* pa1 = A  + (size_t)(tm + cb*16 + (lane>>2))*K + (lane&3)*8;
  const u16* pb0 = Bm + (size_t)(tn + ca*16 + (lane>>2))*K + (lane&3)*8;
  const u16* pb1 = Bm + (size_t)(tn + cb*16 + (lane>>2))*K + (lane&3)*8;
  u16* la0 = &As[ca*512];
  u16* la1 = &As[cb*512];
  u16* lb0 = &Bs[ca*512];
  u16* lb1 = &Bs[cb*512];

  f32x4 acc[4][4] = {};

  const int nk = K >> 5;
  for (int kt = 0; kt < nk; ++kt){
    gload_lds16(pa0, la0);
    gload_lds16(pa1, la1);
    gload_lds16(pb0, lb0);
    gload_lds16(pb1, lb1);
    pa0 += 32; pa1 += 32; pb0 += 32; pb1 += 32;
    __syncthreads();
    bf16x8 af[4], bfr[4];
#pragma unroll
    for (int m = 0; m < 4; ++m)
      af[m] = *reinterpret_cast<const bf16x8*>(&As[(wr*64 + m*16 + lr)*32 + lg*8]);
#pragma unroll
    for (int n = 0; n < 4; ++n)
      bfr[n] = *reinterpret_cast<const bf16x8*>(&Bs[(wc*64 + n*16 + lr)*32 + lg*8]);
#pragma unroll
    for (int m = 0; m < 4; ++m)
#pragma unroll
      for (int n = 0; n < 4; ++n)
        acc[m][n] = mfma16(af[m], bfr[n], acc[m][n]);
    __syncthreads();
  }

  const int rbase = tm + wr*64 + lg*4;
  const int cbase = tn + wc*64 + lr;
#pragma unroll
  for (int m = 0; m < 4; ++m){
#pragma unroll
    for (int n = 0; n < 4; ++n){
#pragma unroll
      for (int r = 0; r < 4; ++r){
        size_t off = (size_t)(rbase + m*16 + r)*N + (cbase + n*16);
        if (WRITE_F32) ((float*)Cp)[off] = acc[m][n][r];
        else           ((u16*)Cp)[off]   = f2bf(acc[m][n][r]);
      }
    }
  }
}

// ---------------- RoPE + scatter ----------------
__global__ void k_rope_scatter(const u16* __restrict__ qkv, const float* __restrict__ cosT,
                               const float* __restrict__ sinT,
                               u16* __restrict__ Q, u16* __restrict__ Ko, u16* __restrict__ V){
  const int row = blockIdx.x;                 // b*L + l
  const int b = row >> 11, l = row & 2047;
  const int t = threadIdx.x;
#pragma unroll
  for (int it = 0; it < 6; ++it){
    int pp = t + it*256;
    u32 xin = *reinterpret_cast<const u32*>(&qkv[(size_t)row*NQKV + pp*2]);
    float x1 = bf2f((u16)(xin & 0xFFFFu));
    float x2 = bf2f((u16)(xin >> 16));
    if (pp < 1280){
      int i = pp & 31;
      float c = cosT[l*32 + i], s = sinT[l*32 + i];
      float y1 = x1*c - x2*s;
      float y2 = x1*s + x2*c;
      if (pp < 1024){
        int hh = pp >> 5, d = (pp & 31)*2;
        u32 o = (u32)f2bf(y1*QSCALE) | ((u32)f2bf(y2*QSCALE) << 16);
        *reinterpret_cast<u32*>(&Q[(((size_t)(b*NHQ + hh))*NL + l)*NHD + d]) = o;
      } else {
        int idx = pp - 1024, kvh = idx >> 5, d = (idx & 31)*2;
        u32 o = (u32)f2bf(y1) | ((u32)f2bf(y2) << 16);
        *reinterpret_cast<u32*>(&Ko[(((size_t)(b*NHKV + kvh))*NL + l)*NHD + d]) = o;
      }
    } else {
      int idx = pp - 1280, kvh = idx >> 5, d = (idx & 31)*2;
      *reinterpret_cast<u32*>(&V[(((size_t)(b*NHKV + kvh))*NL + l)*NHD + d]) = xin;
    }
  }
}

// ---------------- V[b][kvh][l][d] -> VT[b][kvh][d][l] ----------------
__global__ __launch_bounds__(256) void k_transpose(const u16* __restrict__ V, u16* __restrict__ VT){
  __shared__ u16 T[64*72];
  const int bid = blockIdx.x;
  const int slice = bid >> 5, tile = bid & 31;
  const u16* src = V  + (size_t)slice*NL*NHD + (size_t)tile*64*NHD;
  u16*       dst = VT + (size_t)slice*NHD*NL + (size_t)tile*64;
  const int t = threadIdx.x;
  {
    int r = t >> 2, c0 = (t & 3)*16;
    const u16x8* s = reinterpret_cast<const u16x8*>(src + (size_t)r*NHD + c0);
    *reinterpret_cast<u16x8*>(&T[r*72 + c0])     = s[0];
    *reinterpret_cast<u16x8*>(&T[r*72 + c0 + 8]) = s[1];
  }
  __syncthreads();
  {
    int d = t >> 2, l0 = (t & 3)*16;
    u16x8 v0, v1;
#pragma unroll
    for (int j = 0; j < 8; ++j) v0[j] = T[(l0+j)*72 + d];
#pragma unroll
    for (int j = 0; j < 8; ++j) v1[j] = T[(l0+8+j)*72 + d];
    u16* dp = dst + (size_t)d*NL + l0;
    *reinterpret_cast<u16x8*>(dp)     = v0;
    *reinterpret_cast<u16x8*>(dp + 8) = v1;
  }
}

// ---------------- causal GQA flash attention: LDS dual-stream, fixed-shift softmax ----------------
// R8 base (wave owns complementary pair qA=4mb+w, qB=63-qA; one staged KV tile
// feeds both streams; constant per-wave work). NEW: fixed-shift softmax —
// logits are bounded (|S'| <~ 15 in exp2 domain), so P = exp2(S'-24) with NO
// running max, NO rescale, NO per-tile cross-lane ops. Shift cancels in O/lsum;
// bf16 P precision is scale-invariant. Cuts ~60 VALU/tile + the serial max chain.
__device__ __forceinline__ void stage_kv(const u16* __restrict__ Kp, const u16* __restrict__ VTp,
                                         int kvb, u16* lk, u16* lv, int w, int lane){
  const char* ks = (const char*)(Kp + (size_t)kvb*NHD);     // 8KB contiguous
  const char* vs = (const char*)VTp + (size_t)kvb*2;        // 64 rows, stride NL*2
  const int o0 = w*1024 + lane*16;
#pragma unroll
  for (int i = 0; i < 2; ++i){
    int o  = o0 + i*4096;
    int sw = o ^ (((o>>7)&7)<<4);                           // inverse-swizzled source
    gload_lds16(ks + sw, (char*)lk + w*1024 + i*4096);      // LDS base wave-uniform
    int d = o>>7, c = o&127;
    gload_lds16(vs + (size_t)d*(NL*2) + (c ^ ((d&7)<<4)), (char*)lv + w*1024 + i*4096);
  }
}
__device__ __forceinline__ bf16x8 lds16(const u16* base, int row, int colb){
  return *reinterpret_cast<const bf16x8*>((const char*)base + row*128 + (colb ^ ((row&7)<<4)));
}

// One stream's softmax+PV for the current tile (S already computed, exp2 domain).
__device__ __forceinline__ void sm_pv(f32x16& s0, f32x16& s1, f32x16& o0, f32x16& o1,
                                      float& lsum, const bf16x8 vf[8],
                                      int kvb, int qrow, int hi, bool mask){
  if (mask){                                   // wave-uniform branch, edge tile only
#pragma unroll
    for (int r = 0; r < 16; ++r){
      const int kl = (r&3) + 8*(r>>2) + 4*hi;
      if (kvb + kl      > qrow) s0[r] = -1e30f;
      if (kvb + 32 + kl > qrow) s1[r] = -1e30f;
    }
  }
  float p[32];
#pragma unroll
  for (int r = 0; r < 16; ++r){
    p[r]    = exp2_hw(s0[r] - SM_SHIFT);
    p[16+r] = exp2_hw(s1[r] - SM_SHIFT);
  }
  float u[16];
#pragma unroll
  for (int r = 0; r < 16; ++r) u[r] = p[r] + p[16+r];
#pragma unroll
  for (int r = 0; r < 8; ++r)  u[r] += u[r+8];
#pragma unroll
  for (int r = 0; r < 4; ++r)  u[r] += u[r+4];
  lsum += (u[0]+u[1]) + (u[2]+u[3]);
  u32 wds[16];
#pragma unroll
  for (int i = 0; i < 16; ++i) wds[i] = cvtpk(p[2*i], p[2*i+1]);
  bf16x8 pf[4];
#pragma unroll
  for (int fi = 0; fi < 4; ++fi){
    u32 x  = wds[4*fi+0], y  = wds[4*fi+2];
    u32 x2 = wds[4*fi+1], y2 = wds[4*fi+3];
    asm("v_permlane32_swap_b32 %0, %1" : "+v"(x),  "+v"(y));
    asm("v_permlane32_swap_b32 %0, %1" : "+v"(x2), "+v"(y2));
    union { u32 wq[4]; bf16x8 v; } uu;
    uu.wq[0] = x; uu.wq[1] = x2; uu.wq[2] = y; uu.wq[3] = y2;
    pf[fi] = uu.v;
  }
  __builtin_amdgcn_s_setprio(1);
#pragma unroll
  for (int ks = 0; ks < 4; ++ks){
    o0 = mfma32(vf[ks],   pf[ks], o0);
    o1 = mfma32(vf[4+ks], pf[ks], o1);
  }
  __builtin_amdgcn_s_setprio(0);
}

__device__ __forceinline__ void store_o(const f32x16& o0, const f32x16& o1, float lsum,
                                        u16* O, int b, int h, int qrow, int hi){
  float lt = lsum + __shfl_xor(lsum, 32);
  const float inv = 1.0f / lt;
  u16* Op = O + ((size_t)(b*NL + qrow))*ND + h*NHD;
#pragma unroll
  for (int md = 0; md < 2; ++md){
#pragma unroll
    for (int q4 = 0; q4 < 4; ++q4){
      ushort4 sv;
      float a0 = (md ? o1[4*q4+0] : o0[4*q4+0]) * inv;
      float a1 = (md ? o1[4*q4+1] : o0[4*q4+1]) * inv;
      float a2 = (md ? o1[4*q4+2] : o0[4*q4+2]) * inv;
      float a3 = (md ? o1[4*q4+3] : o0[4*q4+3]) * inv;
      sv.x = f2bf(a0); sv.y = f2bf(a1); sv.z = f2bf(a2); sv.w = f2bf(a3);
      *reinterpret_cast<ushort4*>(&Op[md*32 + 8*q4 + 4*hi]) = sv;
    }
  }
}

__global__ __launch_bounds__(256) void k_attn5(const u16* __restrict__ Q, const u16* __restrict__ Kg,
                                               const u16* __restrict__ VT, u16* __restrict__ O){
  __shared__ u16 LK[2][4096];
  __shared__ u16 LV[2][4096];
  const int tid = threadIdx.x, lane = tid & 63, w = tid >> 6;
  const int q32 = lane & 31, hi = lane >> 5;
  const int f = blockIdx.x;                    // 0..511
  const int xcd = f & 7, rest = f >> 3;        // cluster (b,kvh) per XCD for KV L2 reuse
  const int grp = xcd*2 + (rest >> 5);         // 0..15 = (b,kvh)
  const int sub = rest & 31;
  const int b = grp >> 3, kvh = grp & 7;
  const int h = kvh*4 + (sub >> 3);
  const int mb = sub & 7;
  const int qtA = 4*mb + w, qtB = 63 - qtA;
  const u16* Qp  = Q  + ((size_t)(b*NHQ  + h  ))*NL*NHD;
  const u16* Kp  = Kg + ((size_t)(b*NHKV + kvh))*NL*NHD;
  const u16* VTp = VT + ((size_t)(b*NHKV + kvh))*NHD*NL;

  const int qrowA = qtA*32 + q32, qrowB = qtB*32 + q32;
  const int ntA = (qtA*32 + 95) >> 6;
  const int ntB = (qtB*32 + 95) >> 6;
  const int ntblk = ((63 - 4*mb)*32 + 95) >> 6;   // wave 0's ntB = block max

  bf16x8 qfA[4], qfB[4];
#pragma unroll
  for (int ks = 0; ks < 4; ++ks){
    qfA[ks] = *reinterpret_cast<const bf16x8*>(&Qp[(size_t)qrowA*NHD + ks*16 + hi*8]);
    qfB[ks] = *reinterpret_cast<const bf16x8*>(&Qp[(size_t)qrowB*NHD + ks*16 + hi*8]);
  }

  f32x16 oA0 = {}, oA1 = {}, oB0 = {}, oB1 = {};
  float lA = 0.0f, lB = 0.0f;

  stage_kv(Kp, VTp, 0, LK[0], LV[0], w, lane);
  __syncthreads();

#pragma unroll 1
  for (int j = 0; j < ntblk; ++j){
    const int cur = j & 1;
    const u16* lk = LK[cur];
    const u16* lv = LV[cur];
    if (j + 1 < ntblk)
      stage_kv(Kp, VTp, (j+1) << 6, LK[cur^1], LV[cur^1], w, lane);

    const bool actA = j < ntA, actB = j < ntB;
    if (actB){
      const int kvb = j << 6;
      bf16x8 kf[8];
#pragma unroll
      for (int ks = 0; ks < 4; ++ks){
        kf[ks]   = lds16(lk, q32,      ks*32 + hi*16);
        kf[4+ks] = lds16(lk, 32 + q32, ks*32 + hi*16);
      }
      // ---- QK^T for both streams off one kf ----
      f32x16 sB0 = {}, sB1 = {}, sA0 = {}, sA1 = {};
      __builtin_amdgcn_s_setprio(1);
#pragma unroll
      for (int ks = 0; ks < 4; ++ks){
        sB0 = mfma32(kf[ks],   qfB[ks], sB0);
        sB1 = mfma32(kf[4+ks], qfB[ks], sB1);
      }
      if (actA){
#pragma unroll
        for (int ks = 0; ks < 4; ++ks){
          sA0 = mfma32(kf[ks],   qfA[ks], sA0);
          sA1 = mfma32(kf[4+ks], qfA[ks], sA1);
        }
      }
      __builtin_amdgcn_s_setprio(0);
      bf16x8 vf[8];
#pragma unroll
      for (int ks = 0; ks < 4; ++ks){
        vf[ks]   = lds16(lv, q32,      ks*32 + hi*16);
        vf[4+ks] = lds16(lv, 32 + q32, ks*32 + hi*16);
      }
      sm_pv(sB0, sB1, oB0, oB1, lB, vf, kvb, qrowB, hi, j == ntB-1);
      if (actA)
        sm_pv(sA0, sA1, oA0, oA1, lA, vf, kvb, qrowA, hi, j == ntA-1);
    }
    __syncthreads();
  }

  store_o(oA0, oA1, lA, O, b, h, qrowA, hi);
  store_o(oB0, oB1, lB, O, b, h, qrowB, hi);
}

extern "C" void kernel_launch(void* const* d_in, const int* in_sizes, int n_in,
                              void* d_out, int out_size, void* d_ws, size_t ws_size,
                              hipStream_t stream){
  (void)in_sizes; (void)n_in; (void)out_size; (void)ws_size;
  const float* x   = (const float*)d_in[0];
  const int*   pos = (const int*)  d_in[1];
  const float* wq  = (const float*)d_in[2];
  const float* wk  = (const float*)d_in[3];
  const float* wv  = (const float*)d_in[4];
  const float* wo  = (const float*)d_in[5];

  char* ws = (char*)d_ws;
  size_t off = 0;
  auto alloc = [&](size_t bytes) -> void* {
    void* p = ws + off;
    off += (bytes + 255) & ~(size_t)255;
    return p;
  };
  const size_t n_x   = (size_t)NB*NL*ND;
  const size_t n_wq  = (size_t)ND*ND;

  u16* xb    = (u16*)alloc(n_x*2);                       // reused as attn output O
  u16* wqkvb = (u16*)alloc((size_t)NQKV*ND*2);
  u16* wob   = (u16*)alloc(n_wq*2);
  u16* qkv   = (u16*)alloc((size_t)NB*NL*NQKV*2);
  u16* Qb    = (u16*)alloc((size_t)NB*NHQ*NL*NHD*2);
  u16* Kb    = (u16*)alloc((size_t)NB*NHKV*NL*NHD*2);
  u16* Vb    = (u16*)alloc((size_t)NB*NHKV*NL*NHD*2);
  u16* VTb   = (u16*)alloc((size_t)NB*NHKV*NHD*NL*2);
  float* cosT= (float*)alloc((size_t)NL*32*4);
  float* sinT= (float*)alloc((size_t)NL*32*4);

  k_prep<<<CV_TOT/256, 256, 0, stream>>>(x, wq, wk, wv, wo, pos, xb, wqkvb, wob, cosT, sinT);

  k_gemm_nt<0><<<dim3(NQKV/128, (NB*NL)/128), 256, 0, stream>>>(xb, wqkvb, qkv, NB*NL, NQKV, ND);
  k_rope_scatter<<<NB*NL, 256, 0, stream>>>(qkv, cosT, sinT, Qb, Kb, Vb);
  k_transpose<<<NB*NHKV*(NL/64), 256, 0, stream>>>(Vb, VTb);
  k_attn5<<<512, 256, 0, stream>>>(Qb, Kb, VTb, xb);
  k_gemm_nt<1><<<dim3(ND/128, (NB*NL)/128), 256, 0, stream>>>(xb, wob, d_out, NB*NL, ND, ND);
}

// Round 10
// 228.435 us; speedup vs baseline: 1.1501x; 1.0740x over previous
//
#include <hip/hip_runtime.h>
#include <stdint.h>

typedef unsigned short u16;
typedef unsigned int   u32;
typedef __bf16 bf16_t;
typedef bf16_t bf16x8 __attribute__((ext_vector_type(8)));
typedef u16    u16x8  __attribute__((ext_vector_type(8)));
typedef float  f32x4  __attribute__((ext_vector_type(4)));
typedef float  f32x16 __attribute__((ext_vector_type(16)));

#define NB   2
#define NL   2048
#define ND   2048
#define NHQ  32
#define NHKV 8
#define NHD  64
#define NQKV 3072   // D + 2*HKV*HD
#define QSCALE 0.18033688011112042f   // 0.125 * log2(e): softmax runs in exp2 domain
#define SM_SHIFT 24.0f                // fixed softmax shift (logit bound << 24; cancels in O/lsum)

__device__ __forceinline__ u16 f2bf(float x){
  union{float f;u32 u;} v; v.f = x;
  u32 r = v.u + 0x7FFFu + ((v.u >> 16) & 1u);   // RTNE
  return (u16)(r >> 16);
}
__device__ __forceinline__ float bf2f(u16 b){
  union{u32 u;float f;} v; v.u = ((u32)b) << 16; return v.f;
}

__device__ __forceinline__ float exp2_hw(float x){
#if __has_builtin(__builtin_amdgcn_exp2f)
  return __builtin_amdgcn_exp2f(x);
#else
  float r; asm("v_exp_f32 %0, %1" : "=v"(r) : "v"(x)); return r;
#endif
}

__device__ __forceinline__ void gload_lds16(const void* g, void* l){
  auto gp = reinterpret_cast<__attribute__((address_space(1))) u16*>(
      (uintptr_t)g);
  auto lp = reinterpret_cast<__attribute__((address_space(3))) u16*>(
      (uintptr_t)l);
  __builtin_amdgcn_global_load_lds(gp, lp, 16, 0, 0);
}

__device__ __forceinline__ f32x4 mfma16(bf16x8 a, bf16x8 b, f32x4 c){
  return __builtin_amdgcn_mfma_f32_16x16x32_bf16(a, b, c, 0, 0, 0);
}
__device__ __forceinline__ f32x16 mfma32(bf16x8 a, bf16x8 b, f32x16 c){
  return __builtin_amdgcn_mfma_f32_32x32x16_bf16(a, b, c, 0, 0, 0);
}
__device__ __forceinline__ u32 cvtpk(float lo, float hi){
  u32 w;
  asm("v_cvt_pk_bf16_f32 %0, %1, %2" : "=v"(w) : "v"(lo), "v"(hi));
  return w;
}

// ---------------- fused fp32->bf16 converts + RoPE table (one launch) ----------------
#define CV_S1 2097152   // x
#define CV_S2 3145728   // + wq
#define CV_S3 3407872   // + wk
#define CV_S4 3670016   // + wv
#define CV_S5 4718592   // + wo
#define CV_TOT (CV_S5 + 65536)

__global__ void k_prep(const float* __restrict__ x,  const float* __restrict__ wq,
                       const float* __restrict__ wk, const float* __restrict__ wv,
                       const float* __restrict__ wo, const int* __restrict__ pos,
                       u16* __restrict__ xb, u16* __restrict__ wqkvb, u16* __restrict__ wob,
                       float* __restrict__ cosT, float* __restrict__ sinT){
  int i = blockIdx.x * 256 + threadIdx.x;
  if (i < CV_S5){
    const float4* src; ushort4* dst; int off;
    if (i < CV_S1)      { src = (const float4*)x;  dst = (ushort4*)xb;    off = i; }
    else if (i < CV_S2) { src = (const float4*)wq; dst = (ushort4*)wqkvb; off = i - CV_S1; }
    else if (i < CV_S3) { src = (const float4*)wk; dst = (ushort4*)wqkvb + 1048576; off = i - CV_S2; }
    else if (i < CV_S4) { src = (const float4*)wv; dst = (ushort4*)wqkvb + 1310720; off = i - CV_S3; }
    else                { src = (const float4*)wo; dst = (ushort4*)wob;   off = i - CV_S4; }
    float4 f = src[off];
    ushort4 o;
    o.x = f2bf(f.x); o.y = f2bf(f.y); o.z = f2bf(f.z); o.w = f2bf(f.w);
    dst[off] = o;
  } else {
    int idx = i - CV_S5;                         // 65536 = [L][32]
    int l = idx >> 5, k = idx & 31;
    float p = (float)pos[l];
    float inv = __expf(-((float)k * (1.0f/32.0f)) * 9.210340371976184f); // ln(1e4)
    float fr = p * inv;
    cosT[idx] = cosf(fr);
    sinT[idx] = sinf(fr);
  }
}

// ---------------- bf16 NT GEMM: C[M][N] = A[M][K] * B[N][K]^T ----------------
template<int WRITE_F32>
__global__ __launch_bounds__(256) void k_gemm_nt(const u16* __restrict__ A,
                                                 const u16* __restrict__ Bm,
                                                 void* __restrict__ Cp,
                                                 int M, int N, int K){
  __shared__ u16 As[128*32];
  __shared__ u16 Bs[128*32];
  const int tid = threadIdx.x;
  const int lane = tid & 63;
  const int w = tid >> 6;
  const int wr = w >> 1, wc = w & 1;
  const int tm = blockIdx.y * 128, tn = blockIdx.x * 128;
  const int lr = lane & 15, lg = lane >> 4;

  const int ca = 2*w, cb = 2*w+1;
  const u16* pa0 = A  + (size_t)(tm + ca*16 + (lane>>2))*K + (lane&3)*8;
  const u16* pa1 = A  + (size_t)(tm + cb*16 + (lane>>2))*K + (lane&3)*8;
  const u16* pb0 = Bm + (size_t)(tn + ca*16 + (lane>>2))*K + (lane&3)*8;
  const u16* pb1 = Bm + (size_t)(tn + cb*16 + (lane>>2))*K + (lane&3)*8;
  u16* la0 = &As[ca*512];
  u16* la1 = &As[cb*512];
  u16* lb0 = &Bs[ca*512];
  u16* lb1 = &Bs[cb*512];

  f32x4 acc[4][4] = {};

  const int nk = K >> 5;
  for (int kt = 0; kt < nk; ++kt){
    gload_lds16(pa0, la0);
    gload_lds16(pa1, la1);
    gload_lds16(pb0, lb0);
    gload_lds16(pb1, lb1);
    pa0 += 32; pa1 += 32; pb0 += 32; pb1 += 32;
    __syncthreads();
    bf16x8 af[4], bfr[4];
#pragma unroll
    for (int m = 0; m < 4; ++m)
      af[m] = *reinterpret_cast<const bf16x8*>(&As[(wr*64 + m*16 + lr)*32 + lg*8]);
#pragma unroll
    for (int n = 0; n < 4; ++n)
      bfr[n] = *reinterpret_cast<const bf16x8*>(&Bs[(wc*64 + n*16 + lr)*32 + lg*8]);
#pragma unroll
    for (int m = 0; m < 4; ++m)
#pragma unroll
      for (int n = 0; n < 4; ++n)
        acc[m][n] = mfma16(af[m], bfr[n], acc[m][n]);
    __syncthreads();
  }

  const int rbase = tm + wr*64 + lg*4;
  const int cbase = tn + wc*64 + lr;
#pragma unroll
  for (int m = 0; m < 4; ++m){
#pragma unroll
    for (int n = 0; n < 4; ++n){
#pragma unroll
      for (int r = 0; r < 4; ++r){
        size_t off = (size_t)(rbase + m*16 + r)*N + (cbase + n*16);
        if (WRITE_F32) ((float*)Cp)[off] = acc[m][n][r];
        else           ((u16*)Cp)[off]   = f2bf(acc[m][n][r]);
      }
    }
  }
}

// ---------------- RoPE + scatter ----------------
__global__ void k_rope_scatter(const u16* __restrict__ qkv, const float* __restrict__ cosT,
                               const float* __restrict__ sinT,
                               u16* __restrict__ Q, u16* __restrict__ Ko, u16* __restrict__ V){
  const int row = blockIdx.x;                 // b*L + l
  const int b = row >> 11, l = row & 2047;
  const int t = threadIdx.x;
#pragma unroll
  for (int it = 0; it < 6; ++it){
    int pp = t + it*256;
    u32 xin = *reinterpret_cast<const u32*>(&qkv[(size_t)row*NQKV + pp*2]);
    float x1 = bf2f((u16)(xin & 0xFFFFu));
    float x2 = bf2f((u16)(xin >> 16));
    if (pp < 1280){
      int i = pp & 31;
      float c = cosT[l*32 + i], s = sinT[l*32 + i];
      float y1 = x1*c - x2*s;
      float y2 = x1*s + x2*c;
      if (pp < 1024){
        int hh = pp >> 5, d = (pp & 31)*2;
        u32 o = (u32)f2bf(y1*QSCALE) | ((u32)f2bf(y2*QSCALE) << 16);
        *reinterpret_cast<u32*>(&Q[(((size_t)(b*NHQ + hh))*NL + l)*NHD + d]) = o;
      } else {
        int idx = pp - 1024, kvh = idx >> 5, d = (idx & 31)*2;
        u32 o = (u32)f2bf(y1) | ((u32)f2bf(y2) << 16);
        *reinterpret_cast<u32*>(&Ko[(((size_t)(b*NHKV + kvh))*NL + l)*NHD + d]) = o;
      }
    } else {
      int idx = pp - 1280, kvh = idx >> 5, d = (idx & 31)*2;
      *reinterpret_cast<u32*>(&V[(((size_t)(b*NHKV + kvh))*NL + l)*NHD + d]) = xin;
    }
  }
}

// ---------------- V[b][kvh][l][d] -> VT[b][kvh][d][l] ----------------
__global__ __launch_bounds__(256) void k_transpose(const u16* __restrict__ V, u16* __restrict__ VT){
  __shared__ u16 T[64*72];
  const int bid = blockIdx.x;
  const int slice = bid >> 5, tile = bid & 31;
  const u16* src = V  + (size_t)slice*NL*NHD + (size_t)tile*64*NHD;
  u16*       dst = VT + (size_t)slice*NHD*NL + (size_t)tile*64;
  const int t = threadIdx.x;
  {
    int r = t >> 2, c0 = (t & 3)*16;
    const u16x8* s = reinterpret_cast<const u16x8*>(src + (size_t)r*NHD + c0);
    *reinterpret_cast<u16x8*>(&T[r*72 + c0])     = s[0];
    *reinterpret_cast<u16x8*>(&T[r*72 + c0 + 8]) = s[1];
  }
  __syncthreads();
  {
    int d = t >> 2, l0 = (t & 3)*16;
    u16x8 v0, v1;
#pragma unroll
    for (int j = 0; j < 8; ++j) v0[j] = T[(l0+j)*72 + d];
#pragma unroll
    for (int j = 0; j < 8; ++j) v1[j] = T[(l0+8+j)*72 + d];
    u16* dp = dst + (size_t)d*NL + l0;
    *reinterpret_cast<u16x8*>(dp)     = v0;
    *reinterpret_cast<u16x8*>(dp + 8) = v1;
  }
}

// ---------------- causal GQA flash attention: single-stream KVBLK=32, low-VGPR ----------------
// R9 lesson: dual-stream's VGPR floor (~176) locks occupancy at 2 blocks/CU; ~49%
// of the kernel is unhidden stall. This version: 1 wave = 1 q-tile, KVBLK=32,
// p computed IN PLACE on s regs -> ~120 VGPR target (under the 128 cliff) and
// 16KB LDS -> 3-4 blocks/CU. Balance: waves of a block own qt {k,63-k,k+16,47-k}
// (per-block work constant = 130 tile-units); idle waves at the barrier are
// absorbed by co-resident blocks. Fixed-shift softmax kept (exact, no max/rescale).
__device__ __forceinline__ void stage_kv32(const u16* __restrict__ Kp, const u16* __restrict__ VTp,
                                           int kvb, u16* lk, u16* lv, int w, int lane){
  const char* ks = (const char*)(Kp + (size_t)kvb*NHD);   // 4KB contiguous (32 rows x 128B)
  const char* vs = (const char*)VTp + (size_t)kvb*2;      // 64 rows x 64B, stride NL*2
  const int o = w*1024 + lane*16;                         // 0..4095
  const int swk = o ^ (((o>>7)&7)<<4);                    // K: inverse-swizzled source
  gload_lds16(ks + swk, (char*)lk + w*1024);              // LDS dest wave-uniform
  const int row = o >> 6, c = o & 63;                     // V: 64B rows
  gload_lds16(vs + (size_t)row*(NL*2) + (c ^ (((row>>1)&3)<<4)), (char*)lv + w*1024);
}
__device__ __forceinline__ bf16x8 ldsK(const u16* base, int row, int colb){
  return *reinterpret_cast<const bf16x8*>((const char*)base + row*128 + (colb ^ ((row&7)<<4)));
}
__device__ __forceinline__ bf16x8 ldsV(const u16* base, int row, int colb){
  return *reinterpret_cast<const bf16x8*>((const char*)base + row*64 + (colb ^ (((row>>1)&3)<<4)));
}

__global__ __launch_bounds__(256) void k_attn6(const u16* __restrict__ Q, const u16* __restrict__ Kg,
                                               const u16* __restrict__ VT, u16* __restrict__ O){
  __shared__ u16 LK[2][2048];                  // 32 x 64 bf16 = 4KB per buffer
  __shared__ u16 LV[2][2048];
  const int tid = threadIdx.x, lane = tid & 63, w = tid >> 6;
  const int q32 = lane & 31, hi = lane >> 5;
  const int f = blockIdx.x;                    // 0..1023
  const int xcd = f & 7, rest = f >> 3;        // cluster (b,kvh) per XCD for KV L2 reuse
  const int grp = xcd*2 + (rest >> 6);         // 0..15 = (b,kvh)
  const int sub = rest & 63;                   // 4 h x 16 k-slots
  const int b = grp >> 3, kvh = grp & 7;
  const int h = kvh*4 + (sub >> 4);
  const int k = sub & 15;
  const int qt = (w == 0) ? k : (w == 1) ? 63 - k : (w == 2) ? k + 16 : 47 - k;
  const u16* Qp  = Q  + ((size_t)(b*NHQ  + h  ))*NL*NHD;
  const u16* Kp  = Kg + ((size_t)(b*NHKV + kvh))*NL*NHD;
  const u16* VTp = VT + ((size_t)(b*NHKV + kvh))*NHD*NL;

  const int qrow = qt*32 + q32;
  const int ntw   = qt + 1;                    // this wave's trips (32-row KV tiles)
  const int ntblk = 64 - k;                    // block max (wave 1's qt = 63-k)

  bf16x8 qf[4];
#pragma unroll
  for (int ks = 0; ks < 4; ++ks)
    qf[ks] = *reinterpret_cast<const bf16x8*>(&Qp[(size_t)qrow*NHD + ks*16 + hi*8]);

  f32x16 o0 = {}, o1 = {};
  float lsum = 0.0f;

  stage_kv32(Kp, VTp, 0, LK[0], LV[0], w, lane);
  __syncthreads();

#pragma unroll 1
  for (int j = 0; j < ntblk; ++j){
    const int cur = j & 1;
    const u16* lk = LK[cur];
    const u16* lv = LV[cur];
    if (j + 1 < ntblk)
      stage_kv32(Kp, VTp, (j+1) << 5, LK[cur^1], LV[cur^1], w, lane);

    if (j < ntw){
      const int kvb = j << 5;
      bf16x8 kf[4];
#pragma unroll
      for (int ks = 0; ks < 4; ++ks)
        kf[ks] = ldsK(lk, q32, ks*32 + hi*16);
      f32x16 s0 = {};
      __builtin_amdgcn_s_setprio(1);
#pragma unroll
      for (int ks = 0; ks < 4; ++ks)
        s0 = mfma32(kf[ks], qf[ks], s0);
      __builtin_amdgcn_s_setprio(0);
      if (j == ntw - 1){                       // causal edge tile
#pragma unroll
        for (int r = 0; r < 16; ++r){
          const int kl = (r&3) + 8*(r>>2) + 4*hi;
          if (kvb + kl > qrow) s0[r] = -1e30f;
        }
      }
      // p = exp2(s - SHIFT), IN PLACE on s regs (fixed shift, no max/rescale)
#pragma unroll
      for (int r = 0; r < 16; ++r) s0[r] = exp2_hw(s0[r] - SM_SHIFT);
      float u[8];
#pragma unroll
      for (int r = 0; r < 8; ++r)  u[r] = s0[r] + s0[r+8];
#pragma unroll
      for (int r = 0; r < 4; ++r)  u[r] += u[r+4];
      lsum += (u[0]+u[1]) + (u[2]+u[3]);
      // P -> bf16 B-frags (cvt_pk + permlane32_swap)
      u32 wds[8];
#pragma unroll
      for (int i = 0; i < 8; ++i) wds[i] = cvtpk(s0[2*i], s0[2*i+1]);
      bf16x8 pf[2];
#pragma unroll
      for (int fi = 0; fi < 2; ++fi){
        u32 x  = wds[4*fi+0], y  = wds[4*fi+2];
        u32 x2 = wds[4*fi+1], y2 = wds[4*fi+3];
        asm("v_permlane32_swap_b32 %0, %1" : "+v"(x),  "+v"(y));
        asm("v_permlane32_swap_b32 %0, %1" : "+v"(x2), "+v"(y2));
        union { u32 wq[4]; bf16x8 v; } uu;
        uu.wq[0] = x; uu.wq[1] = x2; uu.wq[2] = y; uu.wq[3] = y2;
        pf[fi] = uu.v;
      }
      bf16x8 vf[4];
      vf[0] = ldsV(lv, q32,      hi*16);
      vf[1] = ldsV(lv, q32,      32 + hi*16);
      vf[2] = ldsV(lv, 32 + q32, hi*16);
      vf[3] = ldsV(lv, 32 + q32, 32 + hi*16);
      __builtin_amdgcn_s_setprio(1);
      o0 = mfma32(vf[0], pf[0], o0);
      o0 = mfma32(vf[1], pf[1], o0);
      o1 = mfma32(vf[2], pf[0], o1);
      o1 = mfma32(vf[3], pf[1], o1);
      __builtin_amdgcn_s_setprio(0);
    }
    __syncthreads();
  }

  float lt = lsum + __shfl_xor(lsum, 32);
  const float inv = 1.0f / lt;
  u16* Op = O + ((size_t)(b*NL + qrow))*ND + h*NHD;
#pragma unroll
  for (int md = 0; md < 2; ++md){
#pragma unroll
    for (int q4 = 0; q4 < 4; ++q4){
      ushort4 sv;
      float a0 = (md ? o1[4*q4+0] : o0[4*q4+0]) * inv;
      float a1 = (md ? o1[4*q4+1] : o0[4*q4+1]) * inv;
      float a2 = (md ? o1[4*q4+2] : o0[4*q4+2]) * inv;
      float a3 = (md ? o1[4*q4+3] : o0[4*q4+3]) * inv;
      sv.x = f2bf(a0); sv.y = f2bf(a1); sv.z = f2bf(a2); sv.w = f2bf(a3);
      *reinterpret_cast<ushort4*>(&Op[md*32 + 8*q4 + 4*hi]) = sv;
    }
  }
}

extern "C" void kernel_launch(void* const* d_in, const int* in_sizes, int n_in,
                              void* d_out, int out_size, void* d_ws, size_t ws_size,
                              hipStream_t stream){
  (void)in_sizes; (void)n_in; (void)out_size; (void)ws_size;
  const float* x   = (const float*)d_in[0];
  const int*   pos = (const int*)  d_in[1];
  const float* wq  = (const float*)d_in[2];
  const float* wk  = (const float*)d_in[3];
  const float* wv  = (const float*)d_in[4];
  const float* wo  = (const float*)d_in[5];

  char* ws = (char*)d_ws;
  size_t off = 0;
  auto alloc = [&](size_t bytes) -> void* {
    void* p = ws + off;
    off += (bytes + 255) & ~(size_t)255;
    return p;
  };
  const size_t n_x   = (size_t)NB*NL*ND;
  const size_t n_wq  = (size_t)ND*ND;

  u16* xb    = (u16*)alloc(n_x*2);                       // reused as attn output O
  u16* wqkvb = (u16*)alloc((size_t)NQKV*ND*2);
  u16* wob   = (u16*)alloc(n_wq*2);
  u16* qkv   = (u16*)alloc((size_t)NB*NL*NQKV*2);
  u16* Qb    = (u16*)alloc((size_t)NB*NHQ*NL*NHD*2);
  u16* Kb    = (u16*)alloc((size_t)NB*NHKV*NL*NHD*2);
  u16* Vb    = (u16*)alloc((size_t)NB*NHKV*NL*NHD*2);
  u16* VTb   = (u16*)alloc((size_t)NB*NHKV*NHD*NL*2);
  float* cosT= (float*)alloc((size_t)NL*32*4);
  float* sinT= (float*)alloc((size_t)NL*32*4);

  k_prep<<<CV_TOT/256, 256, 0, stream>>>(x, wq, wk, wv, wo, pos, xb, wqkvb, wob, cosT, sinT);

  k_gemm_nt<0><<<dim3(NQKV/128, (NB*NL)/128), 256, 0, stream>>>(xb, wqkvb, qkv, NB*NL, NQKV, ND);
  k_rope_scatter<<<NB*NL, 256, 0, stream>>>(qkv, cosT, sinT, Qb, Kb, Vb);
  k_transpose<<<NB*NHKV*(NL/64), 256, 0, stream>>>(Vb, VTb);
  k_attn6<<<1024, 256, 0, stream>>>(Qb, Kb, VTb, xb);
  k_gemm_nt<1><<<dim3(ND/128, (NB*NL)/128), 256, 0, stream>>>(xb, wob, d_out, NB*NL, ND, ND);
}

// Round 11
// 217.350 us; speedup vs baseline: 1.2087x; 1.0510x over previous
//
#include <hip/hip_runtime.h>
#include <stdint.h>

typedef unsigned short u16;
typedef unsigned int   u32;
typedef __bf16 bf16_t;
typedef bf16_t bf16x8 __attribute__((ext_vector_type(8)));
typedef u16    u16x8  __attribute__((ext_vector_type(8)));
typedef float  f32x4  __attribute__((ext_vector_type(4)));
typedef float  f32x16 __attribute__((ext_vector_type(16)));

#define NB   2
#define NL   2048
#define ND   2048
#define NHQ  32
#define NHKV 8
#define NHD  64
#define NQKV 3072   // D + 2*HKV*HD
#define QSCALE 0.18033688011112042f   // 0.125 * log2(e): softmax runs in exp2 domain
#define SM_SHIFT 24.0f                // fixed softmax shift (logit bound << 24; cancels in O/lsum)

__device__ __forceinline__ u16 f2bf(float x){
  union{float f;u32 u;} v; v.f = x;
  u32 r = v.u + 0x7FFFu + ((v.u >> 16) & 1u);   // RTNE
  return (u16)(r >> 16);
}
__device__ __forceinline__ float bf2f(u16 b){
  union{u32 u;float f;} v; v.u = ((u32)b) << 16; return v.f;
}

__device__ __forceinline__ float exp2_hw(float x){
#if __has_builtin(__builtin_amdgcn_exp2f)
  return __builtin_amdgcn_exp2f(x);
#else
  float r; asm("v_exp_f32 %0, %1" : "=v"(r) : "v"(x)); return r;
#endif
}

__device__ __forceinline__ void gload_lds16(const void* g, void* l){
  auto gp = reinterpret_cast<__attribute__((address_space(1))) u16*>(
      (uintptr_t)g);
  auto lp = reinterpret_cast<__attribute__((address_space(3))) u16*>(
      (uintptr_t)l);
  __builtin_amdgcn_global_load_lds(gp, lp, 16, 0, 0);
}

__device__ __forceinline__ f32x4 mfma16(bf16x8 a, bf16x8 b, f32x4 c){
  return __builtin_amdgcn_mfma_f32_16x16x32_bf16(a, b, c, 0, 0, 0);
}
__device__ __forceinline__ f32x16 mfma32(bf16x8 a, bf16x8 b, f32x16 c){
  return __builtin_amdgcn_mfma_f32_32x32x16_bf16(a, b, c, 0, 0, 0);
}
__device__ __forceinline__ u32 cvtpk(float lo, float hi){
  u32 w;
  asm("v_cvt_pk_bf16_f32 %0, %1, %2" : "=v"(w) : "v"(lo), "v"(hi));
  return w;
}

// ---------------- fused fp32->bf16 converts + RoPE table (one launch) ----------------
#define CV_S1 2097152   // x
#define CV_S2 3145728   // + wq
#define CV_S3 3407872   // + wk
#define CV_S4 3670016   // + wv
#define CV_S5 4718592   // + wo
#define CV_TOT (CV_S5 + 65536)

__global__ void k_prep(const float* __restrict__ x,  const float* __restrict__ wq,
                       const float* __restrict__ wk, const float* __restrict__ wv,
                       const float* __restrict__ wo, const int* __restrict__ pos,
                       u16* __restrict__ xb, u16* __restrict__ wqkvb, u16* __restrict__ wob,
                       float* __restrict__ cosT, float* __restrict__ sinT){
  int i = blockIdx.x * 256 + threadIdx.x;
  if (i < CV_S5){
    const float4* src; ushort4* dst; int off;
    if (i < CV_S1)      { src = (const float4*)x;  dst = (ushort4*)xb;    off = i; }
    else if (i < CV_S2) { src = (const float4*)wq; dst = (ushort4*)wqkvb; off = i - CV_S1; }
    else if (i < CV_S3) { src = (const float4*)wk; dst = (ushort4*)wqkvb + 1048576; off = i - CV_S2; }
    else if (i < CV_S4) { src = (const float4*)wv; dst = (ushort4*)wqkvb + 1310720; off = i - CV_S3; }
    else                { src = (const float4*)wo; dst = (ushort4*)wob;   off = i - CV_S4; }
    float4 f = src[off];
    ushort4 o;
    o.x = f2bf(f.x); o.y = f2bf(f.y); o.z = f2bf(f.z); o.w = f2bf(f.w);
    dst[off] = o;
  } else {
    int idx = i - CV_S5;                         // 65536 = [L][32]
    int l = idx >> 5, k = idx & 31;
    float p = (float)pos[l];
    float inv = __expf(-((float)k * (1.0f/32.0f)) * 9.210340371976184f); // ln(1e4)
    float fr = p * inv;
    cosT[idx] = cosf(fr);
    sinT[idx] = sinf(fr);
  }
}

// ---------------- 8-phase 256x256 bf16 NT GEMM (T2+T3+T4+T5 port) ----------------
// C[M][N] = A[M][K] * B[N][K]^T. BK=64, 8 waves (2M x 4N), per-wave 128x64.
// LDS 128KB: LA/LB [2][256][64] bf16, XOR-swizzled o^(((o>>7)&7)<<4) (T2,
// both-sides: inverse-swizzled global source + swizzled ds_read — rule21).
// Staging lead = exactly 1 tile (half-tile p staged during phase p) -> the
// read buffer is never written: race-free by construction. vmcnt(0) only at
// the tile boundary, issued 4 phases (~800cyc) after the loads -> ~free.
// Raw s_barrier (no waitcnt drain); lgkmcnt(0)+sched_barrier before MFMA
// (rule18); setprio around the 16-MFMA cluster (T5).
template<int WRITE_F32>
__global__ __launch_bounds__(512) void k_gemm8(const u16* __restrict__ A,
                                               const u16* __restrict__ Bm,
                                               void* __restrict__ Cp,
                                               int M, int N, int K){
  __shared__ u16 LA[2][256*64];
  __shared__ u16 LB[2][256*64];
  const int tid = threadIdx.x;                 // 0..511
  const int lane = tid & 63, w = tid >> 6;     // 8 waves
  const int wr = w >> 2, wc = w & 3;           // 2M x 4N
  const int lr = lane & 15, lg = lane >> 4;
  const int tn = blockIdx.x * 256, tm = blockIdx.y * 256;
  const size_t Kb = (size_t)K * 2;

  const char* Ab = (const char*)A;
  const char* Bb = (const char*)Bm;

  // staging: 4 half-tiles {A0,A1,B0,B1} x 2 loads; 32-bit source offsets
  u32 soff[4][2];
  int ldoff[4][2];
#pragma unroll
  for (int h = 0; h < 4; ++h){
#pragma unroll
    for (int i = 0; i < 2; ++i){
      int o = (h&1)*16384 + i*8192 + tid*16;   // linear LDS byte offset in tile
      int s = o ^ (((o>>7)&7)<<4);             // involution: element that belongs at o
      int row = s >> 7, col = s & 127;
      int trow = (h < 2) ? (tm + row) : (tn + row);
      soff[h][i]  = (u32)((size_t)trow * Kb + col);
      ldoff[h][i] = o;
    }
  }
  // swizzled fragment column offsets (ks=0,1)
  const int c0 = ( lg      ^ (lr & 7)) << 4;
  const int c1 = ((4 + lg) ^ (lr & 7)) << 4;
  const int arow = (wr*128 + lr) * 128;
  const int brow = (wc*64  + lr) * 128;

  f32x4 acc[8][4] = {};
  const int NT = K >> 6;

  // prologue: stage tile 0 into buf 0
#pragma unroll
  for (int h = 0; h < 4; ++h){
    char* base = (h < 2) ? (char*)LA[0] : (char*)LB[0];
    const char* gb = (h < 2) ? Ab : Bb;
    gload_lds16(gb + soff[h][0], base + ldoff[h][0]);
    gload_lds16(gb + soff[h][1], base + ldoff[h][1]);
  }
  asm volatile("s_waitcnt vmcnt(0)" ::: "memory");
  __builtin_amdgcn_s_barrier();

#pragma unroll 1
  for (int kt = 0; kt < NT; ++kt){
    const int cur = kt & 1;
    const char* la = (const char*)LA[cur] + arow;
    const char* lb = (const char*)LB[cur] + brow;
    char* nA = (char*)LA[cur^1];
    char* nB = (char*)LB[cur^1];
    const u32 koff = (u32)(kt+1) * 128;
    const bool pre = (kt + 1 < NT);

    bf16x8 bf[4][2], af[2][2];

#define PH(p)                                                               \
    {                                                                       \
      if (p == 0){                                                          \
        _Pragma("unroll")                                                   \
        for (int n = 0; n < 4; ++n){                                        \
          bf[n][0] = *(const bf16x8*)(lb + n*2048 + c0);                    \
          bf[n][1] = *(const bf16x8*)(lb + n*2048 + c1);                    \
        }                                                                   \
      }                                                                     \
      af[0][0] = *(const bf16x8*)(la + (2*(p)  )*2048 + c0);                \
      af[0][1] = *(const bf16x8*)(la + (2*(p)  )*2048 + c1);                \
      af[1][0] = *(const bf16x8*)(la + (2*(p)+1)*2048 + c0);                \
      af[1][1] = *(const bf16x8*)(la + (2*(p)+1)*2048 + c1);                \
      if (pre){                                                             \
        char* nb_ = ((p) < 2) ? nA : nB;                                    \
        const char* gb_ = ((p) < 2) ? Ab : Bb;                              \
        gload_lds16(gb_ + soff[p][0] + koff, nb_ + ldoff[p][0]);            \
        gload_lds16(gb_ + soff[p][1] + koff, nb_ + ldoff[p][1]);            \
      }                                                                     \
      __builtin_amdgcn_s_barrier();                                         \
      asm volatile("s_waitcnt lgkmcnt(0)" ::: "memory");                    \
      __builtin_amdgcn_sched_barrier(0);                                    \
      __builtin_amdgcn_s_setprio(1);                                        \
      _Pragma("unroll")                                                     \
      for (int n = 0; n < 4; ++n){                                          \
        acc[2*(p)  ][n] = mfma16(af[0][0], bf[n][0], acc[2*(p)  ][n]);      \
        acc[2*(p)  ][n] = mfma16(af[0][1], bf[n][1], acc[2*(p)  ][n]);      \
        acc[2*(p)+1][n] = mfma16(af[1][0], bf[n][0], acc[2*(p)+1][n]);      \
        acc[2*(p)+1][n] = mfma16(af[1][1], bf[n][1], acc[2*(p)+1][n]);      \
      }                                                                     \
      __builtin_amdgcn_s_setprio(0);                                        \
    }

    PH(0)
    __builtin_amdgcn_s_barrier();
    PH(1)
    __builtin_amdgcn_s_barrier();
    PH(2)
    __builtin_amdgcn_s_barrier();
    PH(3)
    asm volatile("s_waitcnt vmcnt(0)" ::: "memory");   // issued 4 phases ago: ~free
    __builtin_amdgcn_s_barrier();
#undef PH
  }

  const int rb = tm + wr*128 + lg*4;
  const int cb = tn + wc*64 + lr;
#pragma unroll
  for (int m = 0; m < 8; ++m){
#pragma unroll
    for (int n = 0; n < 4; ++n){
#pragma unroll
      for (int r = 0; r < 4; ++r){
        size_t off = (size_t)(rb + m*16 + r) * N + (cb + n*16);
        if (WRITE_F32) ((float*)Cp)[off] = acc[m][n][r];
        else           ((u16*)Cp)[off]   = f2bf(acc[m][n][r]);
      }
    }
  }
}

// ---------------- bf16 NT GEMM (128x128 1-phase) — kept for gemm2 (N=2048: only
// 128 blocks at 256-tile would idle half the CUs) ----------------
template<int WRITE_F32>
__global__ __launch_bounds__(256) void k_gemm_nt(const u16* __restrict__ A,
                                                 const u16* __restrict__ Bm,
                                                 void* __restrict__ Cp,
                                                 int M, int N, int K){
  __shared__ u16 As[128*32];
  __shared__ u16 Bs[128*32];
  const int tid = threadIdx.x;
  const int lane = tid & 63;
  const int w = tid >> 6;
  const int wr = w >> 1, wc = w & 1;
  const int tm = blockIdx.y * 128, tn = blockIdx.x * 128;
  const int lr = lane & 15, lg = lane >> 4;

  const int ca = 2*w, cb = 2*w+1;
  const u16* pa0 = A  + (size_t)(tm + ca*16 + (lane>>2))*K + (lane&3)*8;
  const u16* pa1 = A  + (size_t)(tm + cb*16 + (lane>>2))*K + (lane&3)*8;
  const u16* pb0 = Bm + (size_t)(tn + ca*16 + (lane>>2))*K + (lane&3)*8;
  const u16* pb1 = Bm + (size_t)(tn + cb*16 + (lane>>2))*K + (lane&3)*8;
  u16* la0 = &As[ca*512];
  u16* la1 = &As[cb*512];
  u16* lb0 = &Bs[ca*512];
  u16* lb1 = &Bs[cb*512];

  f32x4 acc[4][4] = {};

  const int nk = K >> 5;
  for (int kt = 0; kt < nk; ++kt){
    gload_lds16(pa0, la0);
    gload_lds16(pa1, la1);
    gload_lds16(pb0, lb0);
    gload_lds16(pb1, lb1);
    pa0 += 32; pa1 += 32; pb0 += 32; pb1 += 32;
    __syncthreads();
    bf16x8 af[4], bfr[4];
#pragma unroll
    for (int m = 0; m < 4; ++m)
      af[m] = *reinterpret_cast<const bf16x8*>(&As[(wr*64 + m*16 + lr)*32 + lg*8]);
#pragma unroll
    for (int n = 0; n < 4; ++n)
      bfr[n] = *reinterpret_cast<const bf16x8*>(&Bs[(wc*64 + n*16 + lr)*32 + lg*8]);
#pragma unroll
    for (int m = 0; m < 4; ++m)
#pragma unroll
      for (int n = 0; n < 4; ++n)
        acc[m][n] = mfma16(af[m], bfr[n], acc[m][n]);
    __syncthreads();
  }

  const int rbase = tm + wr*64 + lg*4;
  const int cbase = tn + wc*64 + lr;
#pragma unroll
  for (int m = 0; m < 4; ++m){
#pragma unroll
    for (int n = 0; n < 4; ++n){
#pragma unroll
      for (int r = 0; r < 4; ++r){
        size_t off = (size_t)(rbase + m*16 + r)*N + (cbase + n*16);
        if (WRITE_F32) ((float*)Cp)[off] = acc[m][n][r];
        else           ((u16*)Cp)[off]   = f2bf(acc[m][n][r]);
      }
    }
  }
}

// ---------------- RoPE + scatter ----------------
__global__ void k_rope_scatter(const u16* __restrict__ qkv, const float* __restrict__ cosT,
                               const float* __restrict__ sinT,
                               u16* __restrict__ Q, u16* __restrict__ Ko, u16* __restrict__ V){
  const int row = blockIdx.x;                 // b*L + l
  const int b = row >> 11, l = row & 2047;
  const int t = threadIdx.x;
#pragma unroll
  for (int it = 0; it < 6; ++it){
    int pp = t + it*256;
    u32 xin = *reinterpret_cast<const u32*>(&qkv[(size_t)row*NQKV + pp*2]);
    float x1 = bf2f((u16)(xin & 0xFFFFu));
    float x2 = bf2f((u16)(xin >> 16));
    if (pp < 1280){
      int i = pp & 31;
      float c = cosT[l*32 + i], s = sinT[l*32 + i];
      float y1 = x1*c - x2*s;
      float y2 = x1*s + x2*c;
      if (pp < 1024){
        int hh = pp >> 5, d = (pp & 31)*2;
        u32 o = (u32)f2bf(y1*QSCALE) | ((u32)f2bf(y2*QSCALE) << 16);
        *reinterpret_cast<u32*>(&Q[(((size_t)(b*NHQ + hh))*NL + l)*NHD + d]) = o;
      } else {
        int idx = pp - 1024, kvh = idx >> 5, d = (idx & 31)*2;
        u32 o = (u32)f2bf(y1) | ((u32)f2bf(y2) << 16);
        *reinterpret_cast<u32*>(&Ko[(((size_t)(b*NHKV + kvh))*NL + l)*NHD + d]) = o;
      }
    } else {
      int idx = pp - 1280, kvh = idx >> 5, d = (idx & 31)*2;
      *reinterpret_cast<u32*>(&V[(((size_t)(b*NHKV + kvh))*NL + l)*NHD + d]) = xin;
    }
  }
}

// ---------------- V[b][kvh][l][d] -> VT[b][kvh][d][l] ----------------
__global__ __launch_bounds__(256) void k_transpose(const u16* __restrict__ V, u16* __restrict__ VT){
  __shared__ u16 T[64*72];
  const int bid = blockIdx.x;
  const int slice = bid >> 5, tile = bid & 31;
  const u16* src = V  + (size_t)slice*NL*NHD + (size_t)tile*64*NHD;
  u16*       dst = VT + (size_t)slice*NHD*NL + (size_t)tile*64;
  const int t = threadIdx.x;
  {
    int r = t >> 2, c0 = (t & 3)*16;
    const u16x8* s = reinterpret_cast<const u16x8*>(src + (size_t)r*NHD + c0);
    *reinterpret_cast<u16x8*>(&T[r*72 + c0])     = s[0];
    *reinterpret_cast<u16x8*>(&T[r*72 + c0 + 8]) = s[1];
  }
  __syncthreads();
  {
    int d = t >> 2, l0 = (t & 3)*16;
    u16x8 v0, v1;
#pragma unroll
    for (int j = 0; j < 8; ++j) v0[j] = T[(l0+j)*72 + d];
#pragma unroll
    for (int j = 0; j < 8; ++j) v1[j] = T[(l0+8+j)*72 + d];
    u16* dp = dst + (size_t)d*NL + l0;
    *reinterpret_cast<u16x8*>(dp)     = v0;
    *reinterpret_cast<u16x8*>(dp + 8) = v1;
  }
}

// ---------------- causal GQA flash attention: single-stream KVBLK=32, low-VGPR ----------------
__device__ __forceinline__ void stage_kv32(const u16* __restrict__ Kp, const u16* __restrict__ VTp,
                                           int kvb, u16* lk, u16* lv, int w, int lane){
  const char* ks = (const char*)(Kp + (size_t)kvb*NHD);   // 4KB contiguous (32 rows x 128B)
  const char* vs = (const char*)VTp + (size_t)kvb*2;      // 64 rows x 64B, stride NL*2
  const int o = w*1024 + lane*16;                         // 0..4095
  const int swk = o ^ (((o>>7)&7)<<4);                    // K: inverse-swizzled source
  gload_lds16(ks + swk, (char*)lk + w*1024);              // LDS dest wave-uniform
  const int row = o >> 6, c = o & 63;                     // V: 64B rows
  gload_lds16(vs + (size_t)row*(NL*2) + (c ^ (((row>>1)&3)<<4)), (char*)lv + w*1024);
}
__device__ __forceinline__ bf16x8 ldsK(const u16* base, int row, int colb){
  return *reinterpret_cast<const bf16x8*>((const char*)base + row*128 + (colb ^ ((row&7)<<4)));
}
__device__ __forceinline__ bf16x8 ldsV(const u16* base, int row, int colb){
  return *reinterpret_cast<const bf16x8*>((const char*)base + row*64 + (colb ^ (((row>>1)&3)<<4)));
}

__global__ __launch_bounds__(256) void k_attn6(const u16* __restrict__ Q, const u16* __restrict__ Kg,
                                               const u16* __restrict__ VT, u16* __restrict__ O){
  __shared__ u16 LK[2][2048];                  // 32 x 64 bf16 = 4KB per buffer
  __shared__ u16 LV[2][2048];
  const int tid = threadIdx.x, lane = tid & 63, w = tid >> 6;
  const int q32 = lane & 31, hi = lane >> 5;
  const int f = blockIdx.x;                    // 0..1023
  const int xcd = f & 7, rest = f >> 3;        // cluster (b,kvh) per XCD for KV L2 reuse
  const int grp = xcd*2 + (rest >> 6);         // 0..15 = (b,kvh)
  const int sub = rest & 63;                   // 4 h x 16 k-slots
  const int b = grp >> 3, kvh = grp & 7;
  const int h = kvh*4 + (sub >> 4);
  const int k = sub & 15;
  const int qt = (w == 0) ? k : (w == 1) ? 63 - k : (w == 2) ? k + 16 : 47 - k;
  const u16* Qp  = Q  + ((size_t)(b*NHQ  + h  ))*NL*NHD;
  const u16* Kp  = Kg + ((size_t)(b*NHKV + kvh))*NL*NHD;
  const u16* VTp = VT + ((size_t)(b*NHKV + kvh))*NHD*NL;

  const int qrow = qt*32 + q32;
  const int ntw   = qt + 1;                    // this wave's trips (32-row KV tiles)
  const int ntblk = 64 - k;                    // block max (wave 1's qt = 63-k)

  bf16x8 qf[4];
#pragma unroll
  for (int ks = 0; ks < 4; ++ks)
    qf[ks] = *reinterpret_cast<const bf16x8*>(&Qp[(size_t)qrow*NHD + ks*16 + hi*8]);

  f32x16 o0 = {}, o1 = {};
  float lsum = 0.0f;

  stage_kv32(Kp, VTp, 0, LK[0], LV[0], w, lane);
  __syncthreads();

#pragma unroll 1
  for (int j = 0; j < ntblk; ++j){
    const int cur = j & 1;
    const u16* lk = LK[cur];
    const u16* lv = LV[cur];
    if (j + 1 < ntblk)
      stage_kv32(Kp, VTp, (j+1) << 5, LK[cur^1], LV[cur^1], w, lane);

    if (j < ntw){
      const int kvb = j << 5;
      bf16x8 kf[4];
#pragma unroll
      for (int ks = 0; ks < 4; ++ks)
        kf[ks] = ldsK(lk, q32, ks*32 + hi*16);
      f32x16 s0 = {};
      __builtin_amdgcn_s_setprio(1);
#pragma unroll
      for (int ks = 0; ks < 4; ++ks)
        s0 = mfma32(kf[ks], qf[ks], s0);
      __builtin_amdgcn_s_setprio(0);
      if (j == ntw - 1){                       // causal edge tile
#pragma unroll
        for (int r = 0; r < 16; ++r){
          const int kl = (r&3) + 8*(r>>2) + 4*hi;
          if (kvb + kl > qrow) s0[r] = -1e30f;
        }
      }
      // p = exp2(s - SHIFT), IN PLACE on s regs (fixed shift, no max/rescale)
#pragma unroll
      for (int r = 0; r < 16; ++r) s0[r] = exp2_hw(s0[r] - SM_SHIFT);
      float u[8];
#pragma unroll
      for (int r = 0; r < 8; ++r)  u[r] = s0[r] + s0[r+8];
#pragma unroll
      for (int r = 0; r < 4; ++r)  u[r] += u[r+4];
      lsum += (u[0]+u[1]) + (u[2]+u[3]);
      // P -> bf16 B-frags (cvt_pk + permlane32_swap)
      u32 wds[8];
#pragma unroll
      for (int i = 0; i < 8; ++i) wds[i] = cvtpk(s0[2*i], s0[2*i+1]);
      bf16x8 pf[2];
#pragma unroll
      for (int fi = 0; fi < 2; ++fi){
        u32 x  = wds[4*fi+0], y  = wds[4*fi+2];
        u32 x2 = wds[4*fi+1], y2 = wds[4*fi+3];
        asm("v_permlane32_swap_b32 %0, %1" : "+v"(x),  "+v"(y));
        asm("v_permlane32_swap_b32 %0, %1" : "+v"(x2), "+v"(y2));
        union { u32 wq[4]; bf16x8 v; } uu;
        uu.wq[0] = x; uu.wq[1] = x2; uu.wq[2] = y; uu.wq[3] = y2;
        pf[fi] = uu.v;
      }
      bf16x8 vf[4];
      vf[0] = ldsV(lv, q32,      hi*16);
      vf[1] = ldsV(lv, q32,      32 + hi*16);
      vf[2] = ldsV(lv, 32 + q32, hi*16);
      vf[3] = ldsV(lv, 32 + q32, 32 + hi*16);
      __builtin_amdgcn_s_setprio(1);
      o0 = mfma32(vf[0], pf[0], o0);
      o0 = mfma32(vf[1], pf[1], o0);
      o1 = mfma32(vf[2], pf[0], o1);
      o1 = mfma32(vf[3], pf[1], o1);
      __builtin_amdgcn_s_setprio(0);
    }
    __syncthreads();
  }

  float lt = lsum + __shfl_xor(lsum, 32);
  const float inv = 1.0f / lt;
  u16* Op = O + ((size_t)(b*NL + qrow))*ND + h*NHD;
#pragma unroll
  for (int md = 0; md < 2; ++md){
#pragma unroll
    for (int q4 = 0; q4 < 4; ++q4){
      ushort4 sv;
      float a0 = (md ? o1[4*q4+0] : o0[4*q4+0]) * inv;
      float a1 = (md ? o1[4*q4+1] : o0[4*q4+1]) * inv;
      float a2 = (md ? o1[4*q4+2] : o0[4*q4+2]) * inv;
      float a3 = (md ? o1[4*q4+3] : o0[4*q4+3]) * inv;
      sv.x = f2bf(a0); sv.y = f2bf(a1); sv.z = f2bf(a2); sv.w = f2bf(a3);
      *reinterpret_cast<ushort4*>(&Op[md*32 + 8*q4 + 4*hi]) = sv;
    }
  }
}

extern "C" void kernel_launch(void* const* d_in, const int* in_sizes, int n_in,
                              void* d_out, int out_size, void* d_ws, size_t ws_size,
                              hipStream_t stream){
  (void)in_sizes; (void)n_in; (void)out_size; (void)ws_size;
  const float* x   = (const float*)d_in[0];
  const int*   pos = (const int*)  d_in[1];
  const float* wq  = (const float*)d_in[2];
  const float* wk  = (const float*)d_in[3];
  const float* wv  = (const float*)d_in[4];
  const float* wo  = (const float*)d_in[5];

  char* ws = (char*)d_ws;
  size_t off = 0;
  auto alloc = [&](size_t bytes) -> void* {
    void* p = ws + off;
    off += (bytes + 255) & ~(size_t)255;
    return p;
  };
  const size_t n_x   = (size_t)NB*NL*ND;
  const size_t n_wq  = (size_t)ND*ND;

  u16* xb    = (u16*)alloc(n_x*2);                       // reused as attn output O
  u16* wqkvb = (u16*)alloc((size_t)NQKV*ND*2);
  u16* wob   = (u16*)alloc(n_wq*2);
  u16* qkv   = (u16*)alloc((size_t)NB*NL*NQKV*2);
  u16* Qb    = (u16*)alloc((size_t)NB*NHQ*NL*NHD*2);
  u16* Kb    = (u16*)alloc((size_t)NB*NHKV*NL*NHD*2);
  u16* Vb    = (u16*)alloc((size_t)NB*NHKV*NL*NHD*2);
  u16* VTb   = (u16*)alloc((size_t)NB*NHKV*NHD*NL*2);
  float* cosT= (float*)alloc((size_t)NL*32*4);
  float* sinT= (float*)alloc((size_t)NL*32*4);

  k_prep<<<CV_TOT/256, 256, 0, stream>>>(x, wq, wk, wv, wo, pos, xb, wqkvb, wob, cosT, sinT);

  k_gemm8<0><<<dim3(NQKV/256, (NB*NL)/256), 512, 0, stream>>>(xb, wqkvb, qkv, NB*NL, NQKV, ND);
  k_rope_scatter<<<NB*NL, 256, 0, stream>>>(qkv, cosT, sinT, Qb, Kb, Vb);
  k_transpose<<<NB*NHKV*(NL/64), 256, 0, stream>>>(Vb, VTb);
  k_attn6<<<1024, 256, 0, stream>>>(Qb, Kb, VTb, xb);
  k_gemm_nt<1><<<dim3(ND/128, (NB*NL)/128), 256, 0, stream>>>(xb, wob, d_out, NB*NL, ND, ND);
}

// Round 12
// 189.258 us; speedup vs baseline: 1.3881x; 1.1484x over previous
//
#include <hip/hip_runtime.h>
#include <stdint.h>

typedef unsigned short u16;
typedef unsigned int   u32;
typedef __bf16 bf16_t;
typedef bf16_t bf16x8 __attribute__((ext_vector_type(8)));
typedef u16    u16x8  __attribute__((ext_vector_type(8)));
typedef float  f32x4  __attribute__((ext_vector_type(4)));
typedef float  f32x16 __attribute__((ext_vector_type(16)));

#define NB   2
#define NL   2048
#define ND   2048
#define NHQ  32
#define NHKV 8
#define NHD  64
#define NQKV 3072   // D + 2*HKV*HD
#define QSCALE 0.18033688011112042f   // 0.125 * log2(e): softmax runs in exp2 domain
#define SM_SHIFT 24.0f                // fixed softmax shift (logit bound << 24; cancels in O/lsum)

__device__ __forceinline__ u16 f2bf(float x){
  union{float f;u32 u;} v; v.f = x;
  u32 r = v.u + 0x7FFFu + ((v.u >> 16) & 1u);   // RTNE
  return (u16)(r >> 16);
}
__device__ __forceinline__ float bf2f(u16 b){
  union{u32 u;float f;} v; v.u = ((u32)b) << 16; return v.f;
}

__device__ __forceinline__ float exp2_hw(float x){
#if __has_builtin(__builtin_amdgcn_exp2f)
  return __builtin_amdgcn_exp2f(x);
#else
  float r; asm("v_exp_f32 %0, %1" : "=v"(r) : "v"(x)); return r;
#endif
}

__device__ __forceinline__ void gload_lds16(const void* g, void* l){
  auto gp = reinterpret_cast<__attribute__((address_space(1))) u16*>(
      (uintptr_t)g);
  auto lp = reinterpret_cast<__attribute__((address_space(3))) u16*>(
      (uintptr_t)l);
  __builtin_amdgcn_global_load_lds(gp, lp, 16, 0, 0);
}

__device__ __forceinline__ f32x4 mfma16(bf16x8 a, bf16x8 b, f32x4 c){
  return __builtin_amdgcn_mfma_f32_16x16x32_bf16(a, b, c, 0, 0, 0);
}
__device__ __forceinline__ f32x16 mfma32(bf16x8 a, bf16x8 b, f32x16 c){
  return __builtin_amdgcn_mfma_f32_32x32x16_bf16(a, b, c, 0, 0, 0);
}
__device__ __forceinline__ u32 cvtpk(float lo, float hi){
  u32 w;
  asm("v_cvt_pk_bf16_f32 %0, %1, %2" : "=v"(w) : "v"(lo), "v"(hi));
  return w;
}

// ---------------- fused fp32->bf16 converts + RoPE table (one launch) ----------------
#define CV_S1 2097152   // x
#define CV_S2 3145728   // + wq
#define CV_S3 3407872   // + wk
#define CV_S4 3670016   // + wv
#define CV_S5 4718592   // + wo
#define CV_TOT (CV_S5 + 65536)

__global__ void k_prep(const float* __restrict__ x,  const float* __restrict__ wq,
                       const float* __restrict__ wk, const float* __restrict__ wv,
                       const float* __restrict__ wo, const int* __restrict__ pos,
                       u16* __restrict__ xb, u16* __restrict__ wqkvb, u16* __restrict__ wob,
                       float* __restrict__ cosT, float* __restrict__ sinT){
  int i = blockIdx.x * 256 + threadIdx.x;
  if (i < CV_S5){
    const float4* src; ushort4* dst; int off;
    if (i < CV_S1)      { src = (const float4*)x;  dst = (ushort4*)xb;    off = i; }
    else if (i < CV_S2) { src = (const float4*)wq; dst = (ushort4*)wqkvb; off = i - CV_S1; }
    else if (i < CV_S3) { src = (const float4*)wk; dst = (ushort4*)wqkvb + 1048576; off = i - CV_S2; }
    else if (i < CV_S4) { src = (const float4*)wv; dst = (ushort4*)wqkvb + 1310720; off = i - CV_S3; }
    else                { src = (const float4*)wo; dst = (ushort4*)wob;   off = i - CV_S4; }
    float4 f = src[off];
    ushort4 o;
    o.x = f2bf(f.x); o.y = f2bf(f.y); o.z = f2bf(f.z); o.w = f2bf(f.w);
    dst[off] = o;
  } else {
    int idx = i - CV_S5;                         // 65536 = [L][32]
    int l = idx >> 5, k = idx & 31;
    float p = (float)pos[l];
    float inv = __expf(-((float)k * (1.0f/32.0f)) * 9.210340371976184f); // ln(1e4)
    float fr = p * inv;
    cosT[idx] = cosf(fr);
    sinT[idx] = sinf(fr);
  }
}

// ---------------- 8-phase BMx256 bf16 NT GEMM (T2+T3+T4+T5) ----------------
// C[M][N] = A[M][K] * B[N][K]^T. BK=64, 8 waves (2M x 4N).
// BM=256: per-wave 128x64, LDS 128KB, grid Mx/256. (QKV: 192 blocks)
// BM=128: per-wave 64x64,  LDS  96KB, grid Mx/128. (out-proj: 256 blocks = all CUs)
// XOR swizzle o^(((o>>7)&7)<<4) both-sides (rule21). Staging lead = 1 tile;
// vmcnt(0) only at tile boundary (issued phases earlier -> ~free); raw s_barrier;
// lgkmcnt(0)+sched_barrier before MFMA (rule18); setprio on MFMA cluster (T5).
template<int BM, int WRITE_F32>
__global__ __launch_bounds__(512) void k_gemm8(const u16* __restrict__ A,
                                               const u16* __restrict__ Bm,
                                               void* __restrict__ Cp,
                                               int M, int N, int K){
  constexpr int LA_N = BM/64;            // A loads per thread per K-tile
  constexpr int LN   = LA_N + 4;         // total loads (A + B)
  constexpr int MR   = BM/32;            // m-tiles per wave
  constexpr int MPP  = MR/4;             // m-tiles per phase
  __shared__ u16 LA[2][BM*64];
  __shared__ u16 LB[2][256*64];
  const int tid = threadIdx.x;           // 0..511
  const int lane = tid & 63, w = tid >> 6;
  const int wr = w >> 2, wc = w & 3;     // 2M x 4N
  const int lr = lane & 15, lg = lane >> 4;
  const int tn = blockIdx.x * 256, tm = blockIdx.y * BM;
  const size_t Kb = (size_t)K * 2;
  const char* Ab = (const char*)A;
  const char* Bb = (const char*)Bm;

  u32 soff[LN]; int ldoff[LN];
#pragma unroll
  for (int l = 0; l < LN; ++l){
    int o = ((l < LA_N) ? l : (l - LA_N))*8192 + tid*16;  // linear LDS byte off in tile
    int s = o ^ (((o>>7)&7)<<4);                          // involution
    int row = s >> 7, col = s & 127;
    int trow = (l < LA_N) ? (tm + row) : (tn + row);
    soff[l]  = (u32)((size_t)trow * Kb + col);
    ldoff[l] = o;
  }
  const int c0 = ( lg      ^ (lr & 7)) << 4;
  const int c1 = ((4 + lg) ^ (lr & 7)) << 4;
  const int arow = (wr*(BM/2) + lr) * 128;
  const int brow = (wc*64  + lr) * 128;

  f32x4 acc[MR][4] = {};
  const int NT = K >> 6;

  // prologue: stage tile 0 into buf 0
#pragma unroll
  for (int l = 0; l < LN; ++l){
    char* base = (l < LA_N) ? (char*)LA[0] : (char*)LB[0];
    const char* gb = (l < LA_N) ? Ab : Bb;
    gload_lds16(gb + soff[l], base + ldoff[l]);
  }
  asm volatile("s_waitcnt vmcnt(0)" ::: "memory");
  __builtin_amdgcn_s_barrier();

#pragma unroll 1
  for (int kt = 0; kt < NT; ++kt){
    const int cur = kt & 1;
    const char* la = (const char*)LA[cur] + arow;
    const char* lb = (const char*)LB[cur] + brow;
    char* nA = (char*)LA[cur^1];
    char* nB = (char*)LB[cur^1];
    const u32 koff = (u32)(kt+1) * 128;
    const bool pre = (kt + 1 < NT);

    bf16x8 bf[4][2], af[MPP][2];

#define PH(p)                                                                 \
    {                                                                         \
      if ((p) == 0){                                                          \
        _Pragma("unroll")                                                     \
        for (int n = 0; n < 4; ++n){                                          \
          bf[n][0] = *(const bf16x8*)(lb + n*2048 + c0);                      \
          bf[n][1] = *(const bf16x8*)(lb + n*2048 + c1);                      \
        }                                                                     \
      }                                                                       \
      _Pragma("unroll")                                                       \
      for (int q = 0; q < MPP; ++q){                                          \
        af[q][0] = *(const bf16x8*)(la + (MPP*(p)+q)*2048 + c0);              \
        af[q][1] = *(const bf16x8*)(la + (MPP*(p)+q)*2048 + c1);              \
      }                                                                       \
      if (pre){                                                               \
        _Pragma("unroll")                                                     \
        for (int l = 2*(p); l < 2*(p)+2 && l < LN; ++l){                      \
          char* nb_ = (l < LA_N) ? nA : nB;                                   \
          const char* gb_ = (l < LA_N) ? Ab : Bb;                             \
          gload_lds16(gb_ + soff[l] + koff, nb_ + ldoff[l]);                  \
        }                                                                     \
      }                                                                       \
      __builtin_amdgcn_s_barrier();                                           \
      asm volatile("s_waitcnt lgkmcnt(0)" ::: "memory");                      \
      __builtin_amdgcn_sched_barrier(0);                                      \
      __builtin_amdgcn_s_setprio(1);                                          \
      _Pragma("unroll")                                                       \
      for (int q = 0; q < MPP; ++q){                                          \
        _Pragma("unroll")                                                     \
        for (int n = 0; n < 4; ++n){                                          \
          acc[MPP*(p)+q][n] = mfma16(af[q][0], bf[n][0], acc[MPP*(p)+q][n]);  \
          acc[MPP*(p)+q][n] = mfma16(af[q][1], bf[n][1], acc[MPP*(p)+q][n]);  \
        }                                                                     \
      }                                                                       \
      __builtin_amdgcn_s_setprio(0);                                          \
    }

    PH(0)
    __builtin_amdgcn_s_barrier();
    PH(1)
    __builtin_amdgcn_s_barrier();
    PH(2)
    __builtin_amdgcn_s_barrier();
    PH(3)
    asm volatile("s_waitcnt vmcnt(0)" ::: "memory");   // loads issued phases ago
    __builtin_amdgcn_s_barrier();
#undef PH
  }

  const int rb = tm + wr*(BM/2) + lg*4;
  const int cb = tn + wc*64 + lr;
#pragma unroll
  for (int m = 0; m < MR; ++m){
#pragma unroll
    for (int n = 0; n < 4; ++n){
#pragma unroll
      for (int r = 0; r < 4; ++r){
        size_t off = (size_t)(rb + m*16 + r) * N + (cb + n*16);
        if (WRITE_F32) ((float*)Cp)[off] = acc[m][n][r];
        else           ((u16*)Cp)[off]   = f2bf(acc[m][n][r]);
      }
    }
  }
}

// ---------------- RoPE + scatter ----------------
__global__ void k_rope_scatter(const u16* __restrict__ qkv, const float* __restrict__ cosT,
                               const float* __restrict__ sinT,
                               u16* __restrict__ Q, u16* __restrict__ Ko, u16* __restrict__ V){
  const int row = blockIdx.x;                 // b*L + l
  const int b = row >> 11, l = row & 2047;
  const int t = threadIdx.x;
#pragma unroll
  for (int it = 0; it < 6; ++it){
    int pp = t + it*256;
    u32 xin = *reinterpret_cast<const u32*>(&qkv[(size_t)row*NQKV + pp*2]);
    float x1 = bf2f((u16)(xin & 0xFFFFu));
    float x2 = bf2f((u16)(xin >> 16));
    if (pp < 1280){
      int i = pp & 31;
      float c = cosT[l*32 + i], s = sinT[l*32 + i];
      float y1 = x1*c - x2*s;
      float y2 = x1*s + x2*c;
      if (pp < 1024){
        int hh = pp >> 5, d = (pp & 31)*2;
        u32 o = (u32)f2bf(y1*QSCALE) | ((u32)f2bf(y2*QSCALE) << 16);
        *reinterpret_cast<u32*>(&Q[(((size_t)(b*NHQ + hh))*NL + l)*NHD + d]) = o;
      } else {
        int idx = pp - 1024, kvh = idx >> 5, d = (idx & 31)*2;
        u32 o = (u32)f2bf(y1) | ((u32)f2bf(y2) << 16);
        *reinterpret_cast<u32*>(&Ko[(((size_t)(b*NHKV + kvh))*NL + l)*NHD + d]) = o;
      }
    } else {
      int idx = pp - 1280, kvh = idx >> 5, d = (idx & 31)*2;
      *reinterpret_cast<u32*>(&V[(((size_t)(b*NHKV + kvh))*NL + l)*NHD + d]) = xin;
    }
  }
}

// ---------------- V[b][kvh][l][d] -> VT[b][kvh][d][l] ----------------
__global__ __launch_bounds__(256) void k_transpose(const u16* __restrict__ V, u16* __restrict__ VT){
  __shared__ u16 T[64*72];
  const int bid = blockIdx.x;
  const int slice = bid >> 5, tile = bid & 31;
  const u16* src = V  + (size_t)slice*NL*NHD + (size_t)tile*64*NHD;
  u16*       dst = VT + (size_t)slice*NHD*NL + (size_t)tile*64;
  const int t = threadIdx.x;
  {
    int r = t >> 2, c0 = (t & 3)*16;
    const u16x8* s = reinterpret_cast<const u16x8*>(src + (size_t)r*NHD + c0);
    *reinterpret_cast<u16x8*>(&T[r*72 + c0])     = s[0];
    *reinterpret_cast<u16x8*>(&T[r*72 + c0 + 8]) = s[1];
  }
  __syncthreads();
  {
    int d = t >> 2, l0 = (t & 3)*16;
    u16x8 v0, v1;
#pragma unroll
    for (int j = 0; j < 8; ++j) v0[j] = T[(l0+j)*72 + d];
#pragma unroll
    for (int j = 0; j < 8; ++j) v1[j] = T[(l0+8+j)*72 + d];
    u16* dp = dst + (size_t)d*NL + l0;
    *reinterpret_cast<u16x8*>(dp)     = v0;
    *reinterpret_cast<u16x8*>(dp + 8) = v1;
  }
}

// ---------------- causal GQA flash attention: GQA-block, zero wave idle ----------------
// R11 lesson: qt-mixed blocks idle ~40% of wave-slots at the barrier. Fix:
// block = (b, kvh, qt); the 4 waves = the 4 q-heads of that kv-head. All waves
// share K/V AND have identical trip count qt+1 -> zero intra-block idle.
// Grid balance: boustrophedon qt ordering makes each CU's 4 resident blocks
// sum to constant work; c&7 = kvh pins each KV slice to one XCD (L2 reuse).
__device__ __forceinline__ void stage_kv32(const u16* __restrict__ Kp, const u16* __restrict__ VTp,
                                           int kvb, u16* lk, u16* lv, int w, int lane){
  const char* ks = (const char*)(Kp + (size_t)kvb*NHD);   // 4KB contiguous (32 rows x 128B)
  const char* vs = (const char*)VTp + (size_t)kvb*2;      // 64 rows x 64B, stride NL*2
  const int o = w*1024 + lane*16;                         // 0..4095
  const int swk = o ^ (((o>>7)&7)<<4);                    // K: inverse-swizzled source
  gload_lds16(ks + swk, (char*)lk + w*1024);              // LDS dest wave-uniform
  const int row = o >> 6, c = o & 63;                     // V: 64B rows
  gload_lds16(vs + (size_t)row*(NL*2) + (c ^ (((row>>1)&3)<<4)), (char*)lv + w*1024);
}
__device__ __forceinline__ bf16x8 ldsK(const u16* base, int row, int colb){
  return *reinterpret_cast<const bf16x8*>((const char*)base + row*128 + (colb ^ ((row&7)<<4)));
}
__device__ __forceinline__ bf16x8 ldsV(const u16* base, int row, int colb){
  return *reinterpret_cast<const bf16x8*>((const char*)base + row*64 + (colb ^ (((row>>1)&3)<<4)));
}

__global__ __launch_bounds__(256) void k_attn7(const u16* __restrict__ Q, const u16* __restrict__ Kg,
                                               const u16* __restrict__ VT, u16* __restrict__ O){
  __shared__ u16 LK[2][2048];                  // 32 x 64 bf16 = 4KB per buffer
  __shared__ u16 LV[2][2048];
  const int tid = threadIdx.x, lane = tid & 63, w = tid >> 6;
  const int q32 = lane & 31, hi = lane >> 5;
  const int f = blockIdx.x;                    // 0..1023
  const int round = f >> 8, c = f & 255;
  const int i16 = c >> 4;                      // 0..15
  const int qti = round*16 + ((round & 1) ? (15 - i16) : i16);  // boustrophedon
  const int qt = 63 - qti;
  const int grp = c & 15;                      // (b,kvh); c&7 = kvh = XCD pin
  const int b = grp >> 3, kvh = grp & 7;
  const int h = kvh*4 + w;                     // wave = q-head
  const u16* Qp  = Q  + ((size_t)(b*NHQ  + h  ))*NL*NHD;
  const u16* Kp  = Kg + ((size_t)(b*NHKV + kvh))*NL*NHD;
  const u16* VTp = VT + ((size_t)(b*NHKV + kvh))*NHD*NL;

  const int qrow = qt*32 + q32;
  const int ntw  = qt + 1;                     // SAME for all 4 waves

  bf16x8 qf[4];
#pragma unroll
  for (int ks = 0; ks < 4; ++ks)
    qf[ks] = *reinterpret_cast<const bf16x8*>(&Qp[(size_t)qrow*NHD + ks*16 + hi*8]);

  f32x16 o0 = {}, o1 = {};
  float lsum = 0.0f;

  stage_kv32(Kp, VTp, 0, LK[0], LV[0], w, lane);
  __syncthreads();

#pragma unroll 1
  for (int j = 0; j < ntw; ++j){
    const int cur = j & 1;
    const u16* lk = LK[cur];
    const u16* lv = LV[cur];
    if (j + 1 < ntw)
      stage_kv32(Kp, VTp, (j+1) << 5, LK[cur^1], LV[cur^1], w, lane);

    const int kvb = j << 5;
    bf16x8 kf[4];
#pragma unroll
    for (int ks = 0; ks < 4; ++ks)
      kf[ks] = ldsK(lk, q32, ks*32 + hi*16);
    f32x16 s0 = {};
    __builtin_amdgcn_s_setprio(1);
#pragma unroll
    for (int ks = 0; ks < 4; ++ks)
      s0 = mfma32(kf[ks], qf[ks], s0);
    __builtin_amdgcn_s_setprio(0);
    if (j == ntw - 1){                         // causal edge tile
#pragma unroll
      for (int r = 0; r < 16; ++r){
        const int kl = (r&3) + 8*(r>>2) + 4*hi;
        if (kvb + kl > qrow) s0[r] = -1e30f;
      }
    }
    // p = exp2(s - SHIFT), IN PLACE (fixed shift, no max/rescale)
#pragma unroll
    for (int r = 0; r < 16; ++r) s0[r] = exp2_hw(s0[r] - SM_SHIFT);
    float u[8];
#pragma unroll
    for (int r = 0; r < 8; ++r)  u[r] = s0[r] + s0[r+8];
#pragma unroll
    for (int r = 0; r < 4; ++r)  u[r] += u[r+4];
    lsum += (u[0]+u[1]) + (u[2]+u[3]);
    // P -> bf16 B-frags (cvt_pk + permlane32_swap)
    u32 wds[8];
#pragma unroll
    for (int i = 0; i < 8; ++i) wds[i] = cvtpk(s0[2*i], s0[2*i+1]);
    bf16x8 pf[2];
#pragma unroll
    for (int fi = 0; fi < 2; ++fi){
      u32 x  = wds[4*fi+0], y  = wds[4*fi+2];
      u32 x2 = wds[4*fi+1], y2 = wds[4*fi+3];
      asm("v_permlane32_swap_b32 %0, %1" : "+v"(x),  "+v"(y));
      asm("v_permlane32_swap_b32 %0, %1" : "+v"(x2), "+v"(y2));
      union { u32 wq[4]; bf16x8 v; } uu;
      uu.wq[0] = x; uu.wq[1] = x2; uu.wq[2] = y; uu.wq[3] = y2;
      pf[fi] = uu.v;
    }
    bf16x8 vf[4];
    vf[0] = ldsV(lv, q32,      hi*16);
    vf[1] = ldsV(lv, q32,      32 + hi*16);
    vf[2] = ldsV(lv, 32 + q32, hi*16);
    vf[3] = ldsV(lv, 32 + q32, 32 + hi*16);
    __builtin_amdgcn_s_setprio(1);
    o0 = mfma32(vf[0], pf[0], o0);
    o0 = mfma32(vf[1], pf[1], o0);
    o1 = mfma32(vf[2], pf[0], o1);
    o1 = mfma32(vf[3], pf[1], o1);
    __builtin_amdgcn_s_setprio(0);
    __syncthreads();
  }

  float lt = lsum + __shfl_xor(lsum, 32);
  const float inv = 1.0f / lt;
  u16* Op = O + ((size_t)(b*NL + qrow))*ND + h*NHD;
#pragma unroll
  for (int md = 0; md < 2; ++md){
#pragma unroll
    for (int q4 = 0; q4 < 4; ++q4){
      ushort4 sv;
      float a0 = (md ? o1[4*q4+0] : o0[4*q4+0]) * inv;
      float a1 = (md ? o1[4*q4+1] : o0[4*q4+1]) * inv;
      float a2 = (md ? o1[4*q4+2] : o0[4*q4+2]) * inv;
      float a3 = (md ? o1[4*q4+3] : o0[4*q4+3]) * inv;
      sv.x = f2bf(a0); sv.y = f2bf(a1); sv.z = f2bf(a2); sv.w = f2bf(a3);
      *reinterpret_cast<ushort4*>(&Op[md*32 + 8*q4 + 4*hi]) = sv;
    }
  }
}

extern "C" void kernel_launch(void* const* d_in, const int* in_sizes, int n_in,
                              void* d_out, int out_size, void* d_ws, size_t ws_size,
                              hipStream_t stream){
  (void)in_sizes; (void)n_in; (void)out_size; (void)ws_size;
  const float* x   = (const float*)d_in[0];
  const int*   pos = (const int*)  d_in[1];
  const float* wq  = (const float*)d_in[2];
  const float* wk  = (const float*)d_in[3];
  const float* wv  = (const float*)d_in[4];
  const float* wo  = (const float*)d_in[5];

  char* ws = (char*)d_ws;
  size_t off = 0;
  auto alloc = [&](size_t bytes) -> void* {
    void* p = ws + off;
    off += (bytes + 255) & ~(size_t)255;
    return p;
  };
  const size_t n_x   = (size_t)NB*NL*ND;
  const size_t n_wq  = (size_t)ND*ND;

  u16* xb    = (u16*)alloc(n_x*2);                       // reused as attn output O
  u16* wqkvb = (u16*)alloc((size_t)NQKV*ND*2);
  u16* wob   = (u16*)alloc(n_wq*2);
  u16* qkv   = (u16*)alloc((size_t)NB*NL*NQKV*2);
  u16* Qb    = (u16*)alloc((size_t)NB*NHQ*NL*NHD*2);
  u16* Kb    = (u16*)alloc((size_t)NB*NHKV*NL*NHD*2);
  u16* Vb    = (u16*)alloc((size_t)NB*NHKV*NL*NHD*2);
  u16* VTb   = (u16*)alloc((size_t)NB*NHKV*NHD*NL*2);
  float* cosT= (float*)alloc((size_t)NL*32*4);
  float* sinT= (float*)alloc((size_t)NL*32*4);

  k_prep<<<CV_TOT/256, 256, 0, stream>>>(x, wq, wk, wv, wo, pos, xb, wqkvb, wob, cosT, sinT);

  k_gemm8<256,0><<<dim3(NQKV/256, (NB*NL)/256), 512, 0, stream>>>(xb, wqkvb, qkv, NB*NL, NQKV, ND);
  k_rope_scatter<<<NB*NL, 256, 0, stream>>>(qkv, cosT, sinT, Qb, Kb, Vb);
  k_transpose<<<NB*NHKV*(NL/64), 256, 0, stream>>>(Vb, VTb);
  k_attn7<<<1024, 256, 0, stream>>>(Qb, Kb, VTb, xb);
  k_gemm8<128,1><<<dim3(ND/256, (NB*NL)/128), 512, 0, stream>>>(xb, wob, d_out, NB*NL, ND, ND);
}

// Round 13
// 177.722 us; speedup vs baseline: 1.4782x; 1.0649x over previous
//
#include <hip/hip_runtime.h>
#include <stdint.h>

typedef unsigned short u16;
typedef unsigned int   u32;
typedef __bf16 bf16_t;
typedef bf16_t bf16x8 __attribute__((ext_vector_type(8)));
typedef u16    u16x8  __attribute__((ext_vector_type(8)));
typedef float  f32x4  __attribute__((ext_vector_type(4)));
typedef float  f32x16 __attribute__((ext_vector_type(16)));

#define NB   2
#define NL   2048
#define ND   2048
#define NHQ  32
#define NHKV 8
#define NHD  64
#define NQKV 3072   // D + 2*HKV*HD
#define QSCALE 0.18033688011112042f   // 0.125 * log2(e): softmax runs in exp2 domain
#define SM_SHIFT 24.0f                // fixed softmax shift (logit bound << 24; cancels in O/lsum)

__device__ __forceinline__ u16 f2bf(float x){
  union{float f;u32 u;} v; v.f = x;
  u32 r = v.u + 0x7FFFu + ((v.u >> 16) & 1u);   // RTNE
  return (u16)(r >> 16);
}
__device__ __forceinline__ float bf2f(u16 b){
  union{u32 u;float f;} v; v.u = ((u32)b) << 16; return v.f;
}

__device__ __forceinline__ float exp2_hw(float x){
#if __has_builtin(__builtin_amdgcn_exp2f)
  return __builtin_amdgcn_exp2f(x);
#else
  float r; asm("v_exp_f32 %0, %1" : "=v"(r) : "v"(x)); return r;
#endif
}

__device__ __forceinline__ void gload_lds16(const void* g, void* l){
  auto gp = reinterpret_cast<__attribute__((address_space(1))) u16*>(
      (uintptr_t)g);
  auto lp = reinterpret_cast<__attribute__((address_space(3))) u16*>(
      (uintptr_t)l);
  __builtin_amdgcn_global_load_lds(gp, lp, 16, 0, 0);
}

__device__ __forceinline__ f32x4 mfma16(bf16x8 a, bf16x8 b, f32x4 c){
  return __builtin_amdgcn_mfma_f32_16x16x32_bf16(a, b, c, 0, 0, 0);
}
__device__ __forceinline__ f32x16 mfma32(bf16x8 a, bf16x8 b, f32x16 c){
  return __builtin_amdgcn_mfma_f32_32x32x16_bf16(a, b, c, 0, 0, 0);
}
__device__ __forceinline__ u32 cvtpk(float lo, float hi){
  u32 w;
  asm("v_cvt_pk_bf16_f32 %0, %1, %2" : "=v"(w) : "v"(lo), "v"(hi));
  return w;
}

// ---------------- fused fp32->bf16 converts + RoPE table (one launch) ----------------
#define CV_S1 2097152   // x
#define CV_S2 3145728   // + wq
#define CV_S3 3407872   // + wk
#define CV_S4 3670016   // + wv
#define CV_S5 4718592   // + wo
#define CV_TOT (CV_S5 + 65536)

__global__ void k_prep(const float* __restrict__ x,  const float* __restrict__ wq,
                       const float* __restrict__ wk, const float* __restrict__ wv,
                       const float* __restrict__ wo, const int* __restrict__ pos,
                       u16* __restrict__ xb, u16* __restrict__ wqkvb, u16* __restrict__ wob,
                       float* __restrict__ cosT, float* __restrict__ sinT){
  int i = blockIdx.x * 256 + threadIdx.x;
  if (i < CV_S5){
    const float4* src; ushort4* dst; int off;
    if (i < CV_S1)      { src = (const float4*)x;  dst = (ushort4*)xb;    off = i; }
    else if (i < CV_S2) { src = (const float4*)wq; dst = (ushort4*)wqkvb; off = i - CV_S1; }
    else if (i < CV_S3) { src = (const float4*)wk; dst = (ushort4*)wqkvb + 1048576; off = i - CV_S2; }
    else if (i < CV_S4) { src = (const float4*)wv; dst = (ushort4*)wqkvb + 1310720; off = i - CV_S3; }
    else                { src = (const float4*)wo; dst = (ushort4*)wob;   off = i - CV_S4; }
    float4 f = src[off];
    ushort4 o;
    o.x = f2bf(f.x); o.y = f2bf(f.y); o.z = f2bf(f.z); o.w = f2bf(f.w);
    dst[off] = o;
  } else {
    int idx = i - CV_S5;                         // 65536 = [L][32]
    int l = idx >> 5, k = idx & 31;
    float p = (float)pos[l];
    float inv = __expf(-((float)k * (1.0f/32.0f)) * 9.210340371976184f); // ln(1e4)
    float fr = p * inv;
    cosT[idx] = cosf(fr);
    sinT[idx] = sinf(fr);
  }
}

// ---------------- 8-phase BMxBN bf16 NT GEMM (T2+T3+T4+T5) ----------------
// C[M][N] = A[M][K] * B[N][K]^T. BK=64, 8 waves (2M x 4N).
// R12 lessons: (1) staging 2/phase + vmcnt(0) at boundary = drain on 1-phase-old
// loads (m218's drain-0 case). Fix: issue ALL staging in PH(0) -> loads are 3
// phases (~500cyc) old at the boundary wait -> ~free. (2) grid must cover all
// 256 CUs (1 block/CU at this LDS size): QKV uses BN=192 -> 16x16=256 blocks.
// XOR swizzle o^(((o>>7)&7)<<4) both-sides (rule21); raw s_barrier;
// lgkmcnt(0)+sched_barrier before MFMA (rule18); setprio on MFMA cluster (T5).
template<int BM, int BN, int WRITE_F32>
__global__ __launch_bounds__(512) void k_gemm8(const u16* __restrict__ A,
                                               const u16* __restrict__ Bm,
                                               void* __restrict__ Cp,
                                               int M, int N, int K){
  constexpr int LA_N = BM/64;            // A staging loads per thread per K-tile
  constexpr int LB_N = BN/64;            // B staging loads
  constexpr int LN   = LA_N + LB_N;
  constexpr int MR   = BM/32;            // m-frags per wave
  constexpr int MPP  = MR/4;             // m-frags per phase
  constexpr int NF   = BN/64;            // n-frags per wave (per-wave cols = BN/4)
  __shared__ u16 LA[2][BM*64];
  __shared__ u16 LB[2][BN*64];
  const int tid = threadIdx.x;           // 0..511
  const int lane = tid & 63, w = tid >> 6;
  const int wr = w >> 2, wc = w & 3;     // 2M x 4N
  const int lr = lane & 15, lg = lane >> 4;
  const int tn = blockIdx.x * BN, tm = blockIdx.y * BM;
  const size_t Kb = (size_t)K * 2;
  const char* Ab = (const char*)A;
  const char* Bb = (const char*)Bm;

  u32 soff[LN]; int ldoff[LN];
#pragma unroll
  for (int l = 0; l < LN; ++l){
    int o = ((l < LA_N) ? l : (l - LA_N))*8192 + tid*16;  // linear LDS byte off in tile
    int s = o ^ (((o>>7)&7)<<4);                          // involution
    int row = s >> 7, col = s & 127;
    int trow = (l < LA_N) ? (tm + row) : (tn + row);
    soff[l]  = (u32)((size_t)trow * Kb + col);
    ldoff[l] = o;
  }
  const int c0 = ( lg      ^ (lr & 7)) << 4;
  const int c1 = ((4 + lg) ^ (lr & 7)) << 4;
  const int arow = (wr*(BM/2) + lr) * 128;
  const int brow = (wc*(BN/4) + lr) * 128;

  f32x4 acc[MR][NF] = {};
  const int NT = K >> 6;

  // prologue: stage tile 0 into buf 0
#pragma unroll
  for (int l = 0; l < LN; ++l){
    char* base = (l < LA_N) ? (char*)LA[0] : (char*)LB[0];
    const char* gb = (l < LA_N) ? Ab : Bb;
    gload_lds16(gb + soff[l], base + ldoff[l]);
  }
  asm volatile("s_waitcnt vmcnt(0)" ::: "memory");
  __builtin_amdgcn_s_barrier();

#pragma unroll 1
  for (int kt = 0; kt < NT; ++kt){
    const int cur = kt & 1;
    const char* la = (const char*)LA[cur] + arow;
    const char* lb = (const char*)LB[cur] + brow;
    char* nA = (char*)LA[cur^1];
    char* nB = (char*)LB[cur^1];
    const u32 koff = (u32)(kt+1) * 128;
    const bool pre = (kt + 1 < NT);

    bf16x8 bf[NF][2], af[MPP][2];

#define PH(p)                                                                 \
    {                                                                         \
      if ((p) == 0){                                                          \
        _Pragma("unroll")                                                     \
        for (int n = 0; n < NF; ++n){                                         \
          bf[n][0] = *(const bf16x8*)(lb + n*2048 + c0);                      \
          bf[n][1] = *(const bf16x8*)(lb + n*2048 + c1);                      \
        }                                                                     \
      }                                                                       \
      _Pragma("unroll")                                                       \
      for (int q = 0; q < MPP; ++q){                                          \
        af[q][0] = *(const bf16x8*)(la + (MPP*(p)+q)*2048 + c0);              \
        af[q][1] = *(const bf16x8*)(la + (MPP*(p)+q)*2048 + c1);              \
      }                                                                       \
      if ((p) == 0 && pre){                                                   \
        _Pragma("unroll")                                                     \
        for (int l = 0; l < LN; ++l){                                         \
          char* nb_ = (l < LA_N) ? nA : nB;                                   \
          const char* gb_ = (l < LA_N) ? Ab : Bb;                             \
          gload_lds16(gb_ + soff[l] + koff, nb_ + ldoff[l]);                  \
        }                                                                     \
      }                                                                       \
      __builtin_amdgcn_s_barrier();                                           \
      asm volatile("s_waitcnt lgkmcnt(0)" ::: "memory");                      \
      __builtin_amdgcn_sched_barrier(0);                                      \
      __builtin_amdgcn_s_setprio(1);                                          \
      _Pragma("unroll")                                                       \
      for (int q = 0; q < MPP; ++q){                                          \
        _Pragma("unroll")                                                     \
        for (int n = 0; n < NF; ++n){                                         \
          acc[MPP*(p)+q][n] = mfma16(af[q][0], bf[n][0], acc[MPP*(p)+q][n]);  \
          acc[MPP*(p)+q][n] = mfma16(af[q][1], bf[n][1], acc[MPP*(p)+q][n]);  \
        }                                                                     \
      }                                                                       \
      __builtin_amdgcn_s_setprio(0);                                          \
    }

    PH(0)
    __builtin_amdgcn_s_barrier();
    PH(1)
    __builtin_amdgcn_s_barrier();
    PH(2)
    __builtin_amdgcn_s_barrier();
    PH(3)
    asm volatile("s_waitcnt vmcnt(0)" ::: "memory");   // loads are 3 phases old
    __builtin_amdgcn_s_barrier();
#undef PH
  }

  const int rb = tm + wr*(BM/2) + lg*4;
  const int cb = tn + wc*(BN/4) + lr;
#pragma unroll
  for (int m = 0; m < MR; ++m){
#pragma unroll
    for (int n = 0; n < NF; ++n){
#pragma unroll
      for (int r = 0; r < 4; ++r){
        size_t off = (size_t)(rb + m*16 + r) * N + (cb + n*16);
        if (WRITE_F32) ((float*)Cp)[off] = acc[m][n][r];
        else           ((u16*)Cp)[off]   = f2bf(acc[m][n][r]);
      }
    }
  }
}

// ---------------- RoPE + scatter ----------------
__global__ void k_rope_scatter(const u16* __restrict__ qkv, const float* __restrict__ cosT,
                               const float* __restrict__ sinT,
                               u16* __restrict__ Q, u16* __restrict__ Ko, u16* __restrict__ V){
  const int row = blockIdx.x;                 // b*L + l
  const int b = row >> 11, l = row & 2047;
  const int t = threadIdx.x;
#pragma unroll
  for (int it = 0; it < 6; ++it){
    int pp = t + it*256;
    u32 xin = *reinterpret_cast<const u32*>(&qkv[(size_t)row*NQKV + pp*2]);
    float x1 = bf2f((u16)(xin & 0xFFFFu));
    float x2 = bf2f((u16)(xin >> 16));
    if (pp < 1280){
      int i = pp & 31;
      float c = cosT[l*32 + i], s = sinT[l*32 + i];
      float y1 = x1*c - x2*s;
      float y2 = x1*s + x2*c;
      if (pp < 1024){
        int hh = pp >> 5, d = (pp & 31)*2;
        u32 o = (u32)f2bf(y1*QSCALE) | ((u32)f2bf(y2*QSCALE) << 16);
        *reinterpret_cast<u32*>(&Q[(((size_t)(b*NHQ + hh))*NL + l)*NHD + d]) = o;
      } else {
        int idx = pp - 1024, kvh = idx >> 5, d = (idx & 31)*2;
        u32 o = (u32)f2bf(y1) | ((u32)f2bf(y2) << 16);
        *reinterpret_cast<u32*>(&Ko[(((size_t)(b*NHKV + kvh))*NL + l)*NHD + d]) = o;
      }
    } else {
      int idx = pp - 1280, kvh = idx >> 5, d = (idx & 31)*2;
      *reinterpret_cast<u32*>(&V[(((size_t)(b*NHKV + kvh))*NL + l)*NHD + d]) = xin;
    }
  }
}

// ---------------- V[b][kvh][l][d] -> VT[b][kvh][d][l] ----------------
__global__ __launch_bounds__(256) void k_transpose(const u16* __restrict__ V, u16* __restrict__ VT){
  __shared__ u16 T[64*72];
  const int bid = blockIdx.x;
  const int slice = bid >> 5, tile = bid & 31;
  const u16* src = V  + (size_t)slice*NL*NHD + (size_t)tile*64*NHD;
  u16*       dst = VT + (size_t)slice*NHD*NL + (size_t)tile*64;
  const int t = threadIdx.x;
  {
    int r = t >> 2, c0 = (t & 3)*16;
    const u16x8* s = reinterpret_cast<const u16x8*>(src + (size_t)r*NHD + c0);
    *reinterpret_cast<u16x8*>(&T[r*72 + c0])     = s[0];
    *reinterpret_cast<u16x8*>(&T[r*72 + c0 + 8]) = s[1];
  }
  __syncthreads();
  {
    int d = t >> 2, l0 = (t & 3)*16;
    u16x8 v0, v1;
#pragma unroll
    for (int j = 0; j < 8; ++j) v0[j] = T[(l0+j)*72 + d];
#pragma unroll
    for (int j = 0; j < 8; ++j) v1[j] = T[(l0+8+j)*72 + d];
    u16* dp = dst + (size_t)d*NL + l0;
    *reinterpret_cast<u16x8*>(dp)     = v0;
    *reinterpret_cast<u16x8*>(dp + 8) = v1;
  }
}

// ---------------- causal GQA flash attention: GQA-block, zero wave idle ----------------
__device__ __forceinline__ void stage_kv32(const u16* __restrict__ Kp, const u16* __restrict__ VTp,
                                           int kvb, u16* lk, u16* lv, int w, int lane){
  const char* ks = (const char*)(Kp + (size_t)kvb*NHD);   // 4KB contiguous (32 rows x 128B)
  const char* vs = (const char*)VTp + (size_t)kvb*2;      // 64 rows x 64B, stride NL*2
  const int o = w*1024 + lane*16;                         // 0..4095
  const int swk = o ^ (((o>>7)&7)<<4);                    // K: inverse-swizzled source
  gload_lds16(ks + swk, (char*)lk + w*1024);              // LDS dest wave-uniform
  const int row = o >> 6, c = o & 63;                     // V: 64B rows
  gload_lds16(vs + (size_t)row*(NL*2) + (c ^ (((row>>1)&3)<<4)), (char*)lv + w*1024);
}
__device__ __forceinline__ bf16x8 ldsK(const u16* base, int row, int colb){
  return *reinterpret_cast<const bf16x8*>((const char*)base + row*128 + (colb ^ ((row&7)<<4)));
}
__device__ __forceinline__ bf16x8 ldsV(const u16* base, int row, int colb){
  return *reinterpret_cast<const bf16x8*>((const char*)base + row*64 + (colb ^ (((row>>1)&3)<<4)));
}

__global__ __launch_bounds__(256) void k_attn7(const u16* __restrict__ Q, const u16* __restrict__ Kg,
                                               const u16* __restrict__ VT, u16* __restrict__ O){
  __shared__ u16 LK[2][2048];                  // 32 x 64 bf16 = 4KB per buffer
  __shared__ u16 LV[2][2048];
  const int tid = threadIdx.x, lane = tid & 63, w = tid >> 6;
  const int q32 = lane & 31, hi = lane >> 5;
  const int f = blockIdx.x;                    // 0..1023
  const int round = f >> 8, c = f & 255;
  const int i16 = c >> 4;                      // 0..15
  const int qti = round*16 + ((round & 1) ? (15 - i16) : i16);  // boustrophedon
  const int qt = 63 - qti;
  const int grp = c & 15;                      // (b,kvh); c&7 = kvh = XCD pin
  const int b = grp >> 3, kvh = grp & 7;
  const int h = kvh*4 + w;                     // wave = q-head
  const u16* Qp  = Q  + ((size_t)(b*NHQ  + h  ))*NL*NHD;
  const u16* Kp  = Kg + ((size_t)(b*NHKV + kvh))*NL*NHD;
  const u16* VTp = VT + ((size_t)(b*NHKV + kvh))*NHD*NL;

  const int qrow = qt*32 + q32;
  const int ntw  = qt + 1;                     // SAME for all 4 waves

  bf16x8 qf[4];
#pragma unroll
  for (int ks = 0; ks < 4; ++ks)
    qf[ks] = *reinterpret_cast<const bf16x8*>(&Qp[(size_t)qrow*NHD + ks*16 + hi*8]);

  f32x16 o0 = {}, o1 = {};
  float lsum = 0.0f;

  stage_kv32(Kp, VTp, 0, LK[0], LV[0], w, lane);
  __syncthreads();

#pragma unroll 1
  for (int j = 0; j < ntw; ++j){
    const int cur = j & 1;
    const u16* lk = LK[cur];
    const u16* lv = LV[cur];
    if (j + 1 < ntw)
      stage_kv32(Kp, VTp, (j+1) << 5, LK[cur^1], LV[cur^1], w, lane);

    const int kvb = j << 5;
    bf16x8 kf[4];
#pragma unroll
    for (int ks = 0; ks < 4; ++ks)
      kf[ks] = ldsK(lk, q32, ks*32 + hi*16);
    f32x16 s0 = {};
    __builtin_amdgcn_s_setprio(1);
#pragma unroll
    for (int ks = 0; ks < 4; ++ks)
      s0 = mfma32(kf[ks], qf[ks], s0);
    __builtin_amdgcn_s_setprio(0);
    if (j == ntw - 1){                         // causal edge tile
#pragma unroll
      for (int r = 0; r < 16; ++r){
        const int kl = (r&3) + 8*(r>>2) + 4*hi;
        if (kvb + kl > qrow) s0[r] = -1e30f;
      }
    }
    // p = exp2(s - SHIFT), IN PLACE (fixed shift, no max/rescale)
#pragma unroll
    for (int r = 0; r < 16; ++r) s0[r] = exp2_hw(s0[r] - SM_SHIFT);
    float u[8];
#pragma unroll
    for (int r = 0; r < 8; ++r)  u[r] = s0[r] + s0[r+8];
#pragma unroll
    for (int r = 0; r < 4; ++r)  u[r] += u[r+4];
    lsum += (u[0]+u[1]) + (u[2]+u[3]);
    // P -> bf16 B-frags (cvt_pk + permlane32_swap)
    u32 wds[8];
#pragma unroll
    for (int i = 0; i < 8; ++i) wds[i] = cvtpk(s0[2*i], s0[2*i+1]);
    bf16x8 pf[2];
#pragma unroll
    for (int fi = 0; fi < 2; ++fi){
      u32 x  = wds[4*fi+0], y  = wds[4*fi+2];
      u32 x2 = wds[4*fi+1], y2 = wds[4*fi+3];
      asm("v_permlane32_swap_b32 %0, %1" : "+v"(x),  "+v"(y));
      asm("v_permlane32_swap_b32 %0, %1" : "+v"(x2), "+v"(y2));
      union { u32 wq[4]; bf16x8 v; } uu;
      uu.wq[0] = x; uu.wq[1] = x2; uu.wq[2] = y; uu.wq[3] = y2;
      pf[fi] = uu.v;
    }
    bf16x8 vf[4];
    vf[0] = ldsV(lv, q32,      hi*16);
    vf[1] = ldsV(lv, q32,      32 + hi*16);
    vf[2] = ldsV(lv, 32 + q32, hi*16);
    vf[3] = ldsV(lv, 32 + q32, 32 + hi*16);
    __builtin_amdgcn_s_setprio(1);
    o0 = mfma32(vf[0], pf[0], o0);
    o0 = mfma32(vf[1], pf[1], o0);
    o1 = mfma32(vf[2], pf[0], o1);
    o1 = mfma32(vf[3], pf[1], o1);
    __builtin_amdgcn_s_setprio(0);
    __syncthreads();
  }

  float lt = lsum + __shfl_xor(lsum, 32);
  const float inv = 1.0f / lt;
  u16* Op = O + ((size_t)(b*NL + qrow))*ND + h*NHD;
#pragma unroll
  for (int md = 0; md < 2; ++md){
#pragma unroll
    for (int q4 = 0; q4 < 4; ++q4){
      ushort4 sv;
      float a0 = (md ? o1[4*q4+0] : o0[4*q4+0]) * inv;
      float a1 = (md ? o1[4*q4+1] : o0[4*q4+1]) * inv;
      float a2 = (md ? o1[4*q4+2] : o0[4*q4+2]) * inv;
      float a3 = (md ? o1[4*q4+3] : o0[4*q4+3]) * inv;
      sv.x = f2bf(a0); sv.y = f2bf(a1); sv.z = f2bf(a2); sv.w = f2bf(a3);
      *reinterpret_cast<ushort4*>(&Op[md*32 + 8*q4 + 4*hi]) = sv;
    }
  }
}

extern "C" void kernel_launch(void* const* d_in, const int* in_sizes, int n_in,
                              void* d_out, int out_size, void* d_ws, size_t ws_size,
                              hipStream_t stream){
  (void)in_sizes; (void)n_in; (void)out_size; (void)ws_size;
  const float* x   = (const float*)d_in[0];
  const int*   pos = (const int*)  d_in[1];
  const float* wq  = (const float*)d_in[2];
  const float* wk  = (const float*)d_in[3];
  const float* wv  = (const float*)d_in[4];
  const float* wo  = (const float*)d_in[5];

  char* ws = (char*)d_ws;
  size_t off = 0;
  auto alloc = [&](size_t bytes) -> void* {
    void* p = ws + off;
    off += (bytes + 255) & ~(size_t)255;
    return p;
  };
  const size_t n_x   = (size_t)NB*NL*ND;
  const size_t n_wq  = (size_t)ND*ND;

  u16* xb    = (u16*)alloc(n_x*2);                       // reused as attn output O
  u16* wqkvb = (u16*)alloc((size_t)NQKV*ND*2);
  u16* wob   = (u16*)alloc(n_wq*2);
  u16* qkv   = (u16*)alloc((size_t)NB*NL*NQKV*2);
  u16* Qb    = (u16*)alloc((size_t)NB*NHQ*NL*NHD*2);
  u16* Kb    = (u16*)alloc((size_t)NB*NHKV*NL*NHD*2);
  u16* Vb    = (u16*)alloc((size_t)NB*NHKV*NL*NHD*2);
  u16* VTb   = (u16*)alloc((size_t)NB*NHKV*NHD*NL*2);
  float* cosT= (float*)alloc((size_t)NL*32*4);
  float* sinT= (float*)alloc((size_t)NL*32*4);

  k_prep<<<CV_TOT/256, 256, 0, stream>>>(x, wq, wk, wv, wo, pos, xb, wqkvb, wob, cosT, sinT);

  k_gemm8<256,192,0><<<dim3(NQKV/192, (NB*NL)/256), 512, 0, stream>>>(xb, wqkvb, qkv, NB*NL, NQKV, ND);
  k_rope_scatter<<<NB*NL, 256, 0, stream>>>(qkv, cosT, sinT, Qb, Kb, Vb);
  k_transpose<<<NB*NHKV*(NL/64), 256, 0, stream>>>(Vb, VTb);
  k_attn7<<<1024, 256, 0, stream>>>(Qb, Kb, VTb, xb);
  k_gemm8<128,256,1><<<dim3(ND/256, (NB*NL)/128), 512, 0, stream>>>(xb, wob, d_out, NB*NL, ND, ND);
}

// Round 14
// 175.961 us; speedup vs baseline: 1.4930x; 1.0100x over previous
//
#include <hip/hip_runtime.h>
#include <stdint.h>

typedef unsigned short u16;
typedef unsigned int   u32;
typedef __bf16 bf16_t;
typedef bf16_t bf16x8 __attribute__((ext_vector_type(8)));
typedef u16    u16x8  __attribute__((ext_vector_type(8)));
typedef float  f32x4  __attribute__((ext_vector_type(4)));
typedef float  f32x16 __attribute__((ext_vector_type(16)));

#define NB   2
#define NL   2048
#define ND   2048
#define NHQ  32
#define NHKV 8
#define NHD  64
#define NQKV 3072   // D + 2*HKV*HD
#define QSCALE 0.18033688011112042f   // 0.125 * log2(e): softmax runs in exp2 domain
#define SM_SHIFT 24.0f                // fixed softmax shift (logit bound << 24; cancels in O/lsum)

__device__ __forceinline__ u16 f2bf(float x){
  union{float f;u32 u;} v; v.f = x;
  u32 r = v.u + 0x7FFFu + ((v.u >> 16) & 1u);   // RTNE
  return (u16)(r >> 16);
}
__device__ __forceinline__ float bf2f(u16 b){
  union{u32 u;float f;} v; v.u = ((u32)b) << 16; return v.f;
}

__device__ __forceinline__ float exp2_hw(float x){
#if __has_builtin(__builtin_amdgcn_exp2f)
  return __builtin_amdgcn_exp2f(x);
#else
  float r; asm("v_exp_f32 %0, %1" : "=v"(r) : "v"(x)); return r;
#endif
}

__device__ __forceinline__ void gload_lds16(const void* g, void* l){
  auto gp = reinterpret_cast<__attribute__((address_space(1))) u16*>(
      (uintptr_t)g);
  auto lp = reinterpret_cast<__attribute__((address_space(3))) u16*>(
      (uintptr_t)l);
  __builtin_amdgcn_global_load_lds(gp, lp, 16, 0, 0);
}

__device__ __forceinline__ f32x4 mfma16(bf16x8 a, bf16x8 b, f32x4 c){
  return __builtin_amdgcn_mfma_f32_16x16x32_bf16(a, b, c, 0, 0, 0);
}
__device__ __forceinline__ f32x16 mfma32(bf16x8 a, bf16x8 b, f32x16 c){
  return __builtin_amdgcn_mfma_f32_32x32x16_bf16(a, b, c, 0, 0, 0);
}
__device__ __forceinline__ u32 cvtpk(float lo, float hi){
  u32 w;
  asm("v_cvt_pk_bf16_f32 %0, %1, %2" : "=v"(w) : "v"(lo), "v"(hi));
  return w;
}

// ---------------- fused fp32->bf16 converts + RoPE table (one launch) ----------------
#define CV_S1 2097152   // x
#define CV_S2 3145728   // + wq
#define CV_S3 3407872   // + wk
#define CV_S4 3670016   // + wv
#define CV_S5 4718592   // + wo
#define CV_TOT (CV_S5 + 65536)

__global__ void k_prep(const float* __restrict__ x,  const float* __restrict__ wq,
                       const float* __restrict__ wk, const float* __restrict__ wv,
                       const float* __restrict__ wo, const int* __restrict__ pos,
                       u16* __restrict__ xb, u16* __restrict__ wqkvb, u16* __restrict__ wob,
                       float* __restrict__ cosT, float* __restrict__ sinT){
  int i = blockIdx.x * 256 + threadIdx.x;
  if (i < CV_S5){
    const float4* src; ushort4* dst; int off;
    if (i < CV_S1)      { src = (const float4*)x;  dst = (ushort4*)xb;    off = i; }
    else if (i < CV_S2) { src = (const float4*)wq; dst = (ushort4*)wqkvb; off = i - CV_S1; }
    else if (i < CV_S3) { src = (const float4*)wk; dst = (ushort4*)wqkvb + 1048576; off = i - CV_S2; }
    else if (i < CV_S4) { src = (const float4*)wv; dst = (ushort4*)wqkvb + 1310720; off = i - CV_S3; }
    else                { src = (const float4*)wo; dst = (ushort4*)wob;   off = i - CV_S4; }
    float4 f = src[off];
    ushort4 o;
    o.x = f2bf(f.x); o.y = f2bf(f.y); o.z = f2bf(f.z); o.w = f2bf(f.w);
    dst[off] = o;
  } else {
    int idx = i - CV_S5;                         // 65536 = [L][32]
    int l = idx >> 5, k = idx & 31;
    float p = (float)pos[l];
    float inv = __expf(-((float)k * (1.0f/32.0f)) * 9.210340371976184f); // ln(1e4)
    float fr = p * inv;
    cosT[idx] = cosf(fr);
    sinT[idx] = sinf(fr);
  }
}

// ---------------- 2-phase-per-K-tile BMxBN bf16 NT GEMM (T2+T3+T4+T5) ----------------
// C[M][N] = A[M][K] * B[N][K]^T. BK=64, 8 waves (2M x 4N).
// R13 lesson: 4 small phases/K-tile = 8 barriers charged against 8-12 MFMA each
// -> ~34% MfmaUtil. Intra-tile barriers are schedule-shaping only (waves only
// READ buf[cur] within a tile; the one correctness barrier is the tile-boundary
// one after vmcnt(0)). So: 2 phases/K-tile, 24 (QKV) / 16 (out-proj) MFMA per
// phase, 4 barriers/K-tile. All staging issued in phase 0 (loads ~1.5 phases old
// at the boundary wait). LDS caps occupancy at 1 block/CU -> VGPR is free.
// XOR swizzle o^(((o>>7)&7)<<4) both-sides (rule21); raw s_barrier;
// lgkmcnt(0)+sched_barrier before MFMA (rule18); setprio on MFMA cluster (T5).
template<int BM, int BN, int WRITE_F32>
__global__ __launch_bounds__(512) void k_gemm8(const u16* __restrict__ A,
                                               const u16* __restrict__ Bm,
                                               void* __restrict__ Cp,
                                               int M, int N, int K){
  constexpr int LA_N = BM/64;            // A staging loads per thread per K-tile
  constexpr int LB_N = BN/64;            // B staging loads
  constexpr int LN   = LA_N + LB_N;
  constexpr int MR   = BM/32;            // m-frags per wave
  constexpr int MH   = MR/2;             // m-frags per phase (2 phases)
  constexpr int NF   = BN/64;            // n-frags per wave (per-wave cols = BN/4)
  __shared__ u16 LA[2][BM*64];
  __shared__ u16 LB[2][BN*64];
  const int tid = threadIdx.x;           // 0..511
  const int lane = tid & 63, w = tid >> 6;
  const int wr = w >> 2, wc = w & 3;     // 2M x 4N
  const int lr = lane & 15, lg = lane >> 4;
  const int tn = blockIdx.x * BN, tm = blockIdx.y * BM;
  const size_t Kb = (size_t)K * 2;
  const char* Ab = (const char*)A;
  const char* Bb = (const char*)Bm;

  u32 soff[LN]; int ldoff[LN];
#pragma unroll
  for (int l = 0; l < LN; ++l){
    int o = ((l < LA_N) ? l : (l - LA_N))*8192 + tid*16;  // linear LDS byte off in tile
    int s = o ^ (((o>>7)&7)<<4);                          // involution
    int row = s >> 7, col = s & 127;
    int trow = (l < LA_N) ? (tm + row) : (tn + row);
    soff[l]  = (u32)((size_t)trow * Kb + col);
    ldoff[l] = o;
  }
  const int c0 = ( lg      ^ (lr & 7)) << 4;
  const int c1 = ((4 + lg) ^ (lr & 7)) << 4;
  const int arow = (wr*(BM/2) + lr) * 128;
  const int brow = (wc*(BN/4) + lr) * 128;

  f32x4 acc[MR][NF] = {};
  const int NT = K >> 6;

  // prologue: stage tile 0 into buf 0
#pragma unroll
  for (int l = 0; l < LN; ++l){
    char* base = (l < LA_N) ? (char*)LA[0] : (char*)LB[0];
    const char* gb = (l < LA_N) ? Ab : Bb;
    gload_lds16(gb + soff[l], base + ldoff[l]);
  }
  asm volatile("s_waitcnt vmcnt(0)" ::: "memory");
  __builtin_amdgcn_s_barrier();

#pragma unroll 1
  for (int kt = 0; kt < NT; ++kt){
    const int cur = kt & 1;
    const char* la = (const char*)LA[cur] + arow;
    const char* lb = (const char*)LB[cur] + brow;
    char* nA = (char*)LA[cur^1];
    char* nB = (char*)LB[cur^1];
    const u32 koff = (u32)(kt+1) * 128;
    const bool pre = (kt + 1 < NT);

    bf16x8 bf[NF][2], af[MH][2];

#define PH2(p)                                                                \
    {                                                                         \
      if ((p) == 0){                                                          \
        _Pragma("unroll")                                                     \
        for (int n = 0; n < NF; ++n){                                         \
          bf[n][0] = *(const bf16x8*)(lb + n*2048 + c0);                      \
          bf[n][1] = *(const bf16x8*)(lb + n*2048 + c1);                      \
        }                                                                     \
      }                                                                       \
      _Pragma("unroll")                                                       \
      for (int q = 0; q < MH; ++q){                                           \
        af[q][0] = *(const bf16x8*)(la + (MH*(p)+q)*2048 + c0);               \
        af[q][1] = *(const bf16x8*)(la + (MH*(p)+q)*2048 + c1);               \
      }                                                                       \
      if ((p) == 0 && pre){                                                   \
        _Pragma("unroll")                                                     \
        for (int l = 0; l < LN; ++l){                                         \
          char* nb_ = (l < LA_N) ? nA : nB;                                   \
          const char* gb_ = (l < LA_N) ? Ab : Bb;                             \
          gload_lds16(gb_ + soff[l] + koff, nb_ + ldoff[l]);                  \
        }                                                                     \
      }                                                                       \
      __builtin_amdgcn_s_barrier();                                           \
      asm volatile("s_waitcnt lgkmcnt(0)" ::: "memory");                      \
      __builtin_amdgcn_sched_barrier(0);                                      \
      __builtin_amdgcn_s_setprio(1);                                          \
      _Pragma("unroll")                                                       \
      for (int q = 0; q < MH; ++q){                                           \
        _Pragma("unroll")                                                     \
        for (int n = 0; n < NF; ++n){                                         \
          acc[MH*(p)+q][n] = mfma16(af[q][0], bf[n][0], acc[MH*(p)+q][n]);    \
          acc[MH*(p)+q][n] = mfma16(af[q][1], bf[n][1], acc[MH*(p)+q][n]);    \
        }                                                                     \
      }                                                                       \
      __builtin_amdgcn_s_setprio(0);                                          \
    }

    PH2(0)
    __builtin_amdgcn_s_barrier();
    PH2(1)
    asm volatile("s_waitcnt vmcnt(0)" ::: "memory");   // loads ~1.5 phases old
    __builtin_amdgcn_s_barrier();
#undef PH2
  }

  const int rb = tm + wr*(BM/2) + lg*4;
  const int cb = tn + wc*(BN/4) + lr;
#pragma unroll
  for (int m = 0; m < MR; ++m){
#pragma unroll
    for (int n = 0; n < NF; ++n){
#pragma unroll
      for (int r = 0; r < 4; ++r){
        size_t off = (size_t)(rb + m*16 + r) * N + (cb + n*16);
        if (WRITE_F32) ((float*)Cp)[off] = acc[m][n][r];
        else           ((u16*)Cp)[off]   = f2bf(acc[m][n][r]);
      }
    }
  }
}

// ---------------- RoPE + scatter ----------------
__global__ void k_rope_scatter(const u16* __restrict__ qkv, const float* __restrict__ cosT,
                               const float* __restrict__ sinT,
                               u16* __restrict__ Q, u16* __restrict__ Ko, u16* __restrict__ V){
  const int row = blockIdx.x;                 // b*L + l
  const int b = row >> 11, l = row & 2047;
  const int t = threadIdx.x;
#pragma unroll
  for (int it = 0; it < 6; ++it){
    int pp = t + it*256;
    u32 xin = *reinterpret_cast<const u32*>(&qkv[(size_t)row*NQKV + pp*2]);
    float x1 = bf2f((u16)(xin & 0xFFFFu));
    float x2 = bf2f((u16)(xin >> 16));
    if (pp < 1280){
      int i = pp & 31;
      float c = cosT[l*32 + i], s = sinT[l*32 + i];
      float y1 = x1*c - x2*s;
      float y2 = x1*s + x2*c;
      if (pp < 1024){
        int hh = pp >> 5, d = (pp & 31)*2;
        u32 o = (u32)f2bf(y1*QSCALE) | ((u32)f2bf(y2*QSCALE) << 16);
        *reinterpret_cast<u32*>(&Q[(((size_t)(b*NHQ + hh))*NL + l)*NHD + d]) = o;
      } else {
        int idx = pp - 1024, kvh = idx >> 5, d = (idx & 31)*2;
        u32 o = (u32)f2bf(y1) | ((u32)f2bf(y2) << 16);
        *reinterpret_cast<u32*>(&Ko[(((size_t)(b*NHKV + kvh))*NL + l)*NHD + d]) = o;
      }
    } else {
      int idx = pp - 1280, kvh = idx >> 5, d = (idx & 31)*2;
      *reinterpret_cast<u32*>(&V[(((size_t)(b*NHKV + kvh))*NL + l)*NHD + d]) = xin;
    }
  }
}

// ---------------- V[b][kvh][l][d] -> VT[b][kvh][d][l] ----------------
__global__ __launch_bounds__(256) void k_transpose(const u16* __restrict__ V, u16* __restrict__ VT){
  __shared__ u16 T[64*72];
  const int bid = blockIdx.x;
  const int slice = bid >> 5, tile = bid & 31;
  const u16* src = V  + (size_t)slice*NL*NHD + (size_t)tile*64*NHD;
  u16*       dst = VT + (size_t)slice*NHD*NL + (size_t)tile*64;
  const int t = threadIdx.x;
  {
    int r = t >> 2, c0 = (t & 3)*16;
    const u16x8* s = reinterpret_cast<const u16x8*>(src + (size_t)r*NHD + c0);
    *reinterpret_cast<u16x8*>(&T[r*72 + c0])     = s[0];
    *reinterpret_cast<u16x8*>(&T[r*72 + c0 + 8]) = s[1];
  }
  __syncthreads();
  {
    int d = t >> 2, l0 = (t & 3)*16;
    u16x8 v0, v1;
#pragma unroll
    for (int j = 0; j < 8; ++j) v0[j] = T[(l0+j)*72 + d];
#pragma unroll
    for (int j = 0; j < 8; ++j) v1[j] = T[(l0+8+j)*72 + d];
    u16* dp = dst + (size_t)d*NL + l0;
    *reinterpret_cast<u16x8*>(dp)     = v0;
    *reinterpret_cast<u16x8*>(dp + 8) = v1;
  }
}

// ---------------- causal GQA flash attention: GQA-block, zero wave idle ----------------
__device__ __forceinline__ void stage_kv32(const u16* __restrict__ Kp, const u16* __restrict__ VTp,
                                           int kvb, u16* lk, u16* lv, int w, int lane){
  const char* ks = (const char*)(Kp + (size_t)kvb*NHD);   // 4KB contiguous (32 rows x 128B)
  const char* vs = (const char*)VTp + (size_t)kvb*2;      // 64 rows x 64B, stride NL*2
  const int o = w*1024 + lane*16;                         // 0..4095
  const int swk = o ^ (((o>>7)&7)<<4);                    // K: inverse-swizzled source
  gload_lds16(ks + swk, (char*)lk + w*1024);              // LDS dest wave-uniform
  const int row = o >> 6, c = o & 63;                     // V: 64B rows
  gload_lds16(vs + (size_t)row*(NL*2) + (c ^ (((row>>1)&3)<<4)), (char*)lv + w*1024);
}
__device__ __forceinline__ bf16x8 ldsK(const u16* base, int row, int colb){
  return *reinterpret_cast<const bf16x8*>((const char*)base + row*128 + (colb ^ ((row&7)<<4)));
}
__device__ __forceinline__ bf16x8 ldsV(const u16* base, int row, int colb){
  return *reinterpret_cast<const bf16x8*>((const char*)base + row*64 + (colb ^ (((row>>1)&3)<<4)));
}

__global__ __launch_bounds__(256) void k_attn7(const u16* __restrict__ Q, const u16* __restrict__ Kg,
                                               const u16* __restrict__ VT, u16* __restrict__ O){
  __shared__ u16 LK[2][2048];                  // 32 x 64 bf16 = 4KB per buffer
  __shared__ u16 LV[2][2048];
  const int tid = threadIdx.x, lane = tid & 63, w = tid >> 6;
  const int q32 = lane & 31, hi = lane >> 5;
  const int f = blockIdx.x;                    // 0..1023
  const int round = f >> 8, c = f & 255;
  const int i16 = c >> 4;                      // 0..15
  const int qti = round*16 + ((round & 1) ? (15 - i16) : i16);  // boustrophedon
  const int qt = 63 - qti;
  const int grp = c & 15;                      // (b,kvh); c&7 = kvh = XCD pin
  const int b = grp >> 3, kvh = grp & 7;
  const int h = kvh*4 + w;                     // wave = q-head
  const u16* Qp  = Q  + ((size_t)(b*NHQ  + h  ))*NL*NHD;
  const u16* Kp  = Kg + ((size_t)(b*NHKV + kvh))*NL*NHD;
  const u16* VTp = VT + ((size_t)(b*NHKV + kvh))*NHD*NL;

  const int qrow = qt*32 + q32;
  const int ntw  = qt + 1;                     // SAME for all 4 waves

  bf16x8 qf[4];
#pragma unroll
  for (int ks = 0; ks < 4; ++ks)
    qf[ks] = *reinterpret_cast<const bf16x8*>(&Qp[(size_t)qrow*NHD + ks*16 + hi*8]);

  f32x16 o0 = {}, o1 = {};
  float lsum = 0.0f;

  stage_kv32(Kp, VTp, 0, LK[0], LV[0], w, lane);
  __syncthreads();

#pragma unroll 1
  for (int j = 0; j < ntw; ++j){
    const int cur = j & 1;
    const u16* lk = LK[cur];
    const u16* lv = LV[cur];
    if (j + 1 < ntw)
      stage_kv32(Kp, VTp, (j+1) << 5, LK[cur^1], LV[cur^1], w, lane);

    const int kvb = j << 5;
    bf16x8 kf[4];
#pragma unroll
    for (int ks = 0; ks < 4; ++ks)
      kf[ks] = ldsK(lk, q32, ks*32 + hi*16);
    f32x16 s0 = {};
    __builtin_amdgcn_s_setprio(1);
#pragma unroll
    for (int ks = 0; ks < 4; ++ks)
      s0 = mfma32(kf[ks], qf[ks], s0);
    __builtin_amdgcn_s_setprio(0);
    if (j == ntw - 1){                         // causal edge tile
#pragma unroll
      for (int r = 0; r < 16; ++r){
        const int kl = (r&3) + 8*(r>>2) + 4*hi;
        if (kvb + kl > qrow) s0[r] = -1e30f;
      }
    }
    // p = exp2(s - SHIFT), IN PLACE (fixed shift, no max/rescale)
#pragma unroll
    for (int r = 0; r < 16; ++r) s0[r] = exp2_hw(s0[r] - SM_SHIFT);
    float u[8];
#pragma unroll
    for (int r = 0; r < 8; ++r)  u[r] = s0[r] + s0[r+8];
#pragma unroll
    for (int r = 0; r < 4; ++r)  u[r] += u[r+4];
    lsum += (u[0]+u[1]) + (u[2]+u[3]);
    // P -> bf16 B-frags (cvt_pk + permlane32_swap)
    u32 wds[8];
#pragma unroll
    for (int i = 0; i < 8; ++i) wds[i] = cvtpk(s0[2*i], s0[2*i+1]);
    bf16x8 pf[2];
#pragma unroll
    for (int fi = 0; fi < 2; ++fi){
      u32 x  = wds[4*fi+0], y  = wds[4*fi+2];
      u32 x2 = wds[4*fi+1], y2 = wds[4*fi+3];
      asm("v_permlane32_swap_b32 %0, %1" : "+v"(x),  "+v"(y));
      asm("v_permlane32_swap_b32 %0, %1" : "+v"(x2), "+v"(y2));
      union { u32 wq[4]; bf16x8 v; } uu;
      uu.wq[0] = x; uu.wq[1] = x2; uu.wq[2] = y; uu.wq[3] = y2;
      pf[fi] = uu.v;
    }
    bf16x8 vf[4];
    vf[0] = ldsV(lv, q32,      hi*16);
    vf[1] = ldsV(lv, q32,      32 + hi*16);
    vf[2] = ldsV(lv, 32 + q32, hi*16);
    vf[3] = ldsV(lv, 32 + q32, 32 + hi*16);
    __builtin_amdgcn_s_setprio(1);
    o0 = mfma32(vf[0], pf[0], o0);
    o0 = mfma32(vf[1], pf[1], o0);
    o1 = mfma32(vf[2], pf[0], o1);
    o1 = mfma32(vf[3], pf[1], o1);
    __builtin_amdgcn_s_setprio(0);
    __syncthreads();
  }

  float lt = lsum + __shfl_xor(lsum, 32);
  const float inv = 1.0f / lt;
  u16* Op = O + ((size_t)(b*NL + qrow))*ND + h*NHD;
#pragma unroll
  for (int md = 0; md < 2; ++md){
#pragma unroll
    for (int q4 = 0; q4 < 4; ++q4){
      ushort4 sv;
      float a0 = (md ? o1[4*q4+0] : o0[4*q4+0]) * inv;
      float a1 = (md ? o1[4*q4+1] : o0[4*q4+1]) * inv;
      float a2 = (md ? o1[4*q4+2] : o0[4*q4+2]) * inv;
      float a3 = (md ? o1[4*q4+3] : o0[4*q4+3]) * inv;
      sv.x = f2bf(a0); sv.y = f2bf(a1); sv.z = f2bf(a2); sv.w = f2bf(a3);
      *reinterpret_cast<ushort4*>(&Op[md*32 + 8*q4 + 4*hi]) = sv;
    }
  }
}

extern "C" void kernel_launch(void* const* d_in, const int* in_sizes, int n_in,
                              void* d_out, int out_size, void* d_ws, size_t ws_size,
                              hipStream_t stream){
  (void)in_sizes; (void)n_in; (void)out_size; (void)ws_size;
  const float* x   = (const float*)d_in[0];
  const int*   pos = (const int*)  d_in[1];
  const float* wq  = (const float*)d_in[2];
  const float* wk  = (const float*)d_in[3];
  const float* wv  = (const float*)d_in[4];
  const float* wo  = (const float*)d_in[5];

  char* ws = (char*)d_ws;
  size_t off = 0;
  auto alloc = [&](size_t bytes) -> void* {
    void* p = ws + off;
    off += (bytes + 255) & ~(size_t)255;
    return p;
  };
  const size_t n_x   = (size_t)NB*NL*ND;
  const size_t n_wq  = (size_t)ND*ND;

  u16* xb    = (u16*)alloc(n_x*2);                       // reused as attn output O
  u16* wqkvb = (u16*)alloc((size_t)NQKV*ND*2);
  u16* wob   = (u16*)alloc(n_wq*2);
  u16* qkv   = (u16*)alloc((size_t)NB*NL*NQKV*2);
  u16* Qb    = (u16*)alloc((size_t)NB*NHQ*NL*NHD*2);
  u16* Kb    = (u16*)alloc((size_t)NB*NHKV*NL*NHD*2);
  u16* Vb    = (u16*)alloc((size_t)NB*NHKV*NL*NHD*2);
  u16* VTb   = (u16*)alloc((size_t)NB*NHKV*NHD*NL*2);
  float* cosT= (float*)alloc((size_t)NL*32*4);
  float* sinT= (float*)alloc((size_t)NL*32*4);

  k_prep<<<CV_TOT/256, 256, 0, stream>>>(x, wq, wk, wv, wo, pos, xb, wqkvb, wob, cosT, sinT);

  k_gemm8<256,192,0><<<dim3(NQKV/192, (NB*NL)/256), 512, 0, stream>>>(xb, wqkvb, qkv, NB*NL, NQKV, ND);
  k_rope_scatter<<<NB*NL, 256, 0, stream>>>(qkv, cosT, sinT, Qb, Kb, Vb);
  k_transpose<<<NB*NHKV*(NL/64), 256, 0, stream>>>(Vb, VTb);
  k_attn7<<<1024, 256, 0, stream>>>(Qb, Kb, VTb, xb);
  k_gemm8<128,256,1><<<dim3(ND/256, (NB*NL)/128), 512, 0, stream>>>(xb, wob, d_out, NB*NL, ND, ND);
}